// Round 11
// baseline (253.601 us; speedup 1.0000x reference)
//
#include <hip/hip_runtime.h>

// Problem constants
#define S_LEN 2048
#define NTOK  4096      // B*S = 2*2048
#define HID   2048
#define NQH   16
#define NKVH  4
#define HD    128
#define NCOLS 5120      // 2048 q + 512 k + 512 v + 2048 gate

using bf16x8 = __attribute__((ext_vector_type(8))) __bf16;
using f32x4  = __attribute__((ext_vector_type(4))) float;

__device__ inline unsigned short f2bf(float f) {
  unsigned int u = __builtin_bit_cast(unsigned int, f);
  u += 0x7FFF + ((u >> 16) & 1);   // round-to-nearest-even
  return (unsigned short)(u >> 16);
}
__device__ inline float bf2f(unsigned short u) {
  unsigned int v = (unsigned int)u << 16;
  return __builtin_bit_cast(float, v);
}

// async global->LDS, 16B per lane. LDS ptr must be wave-uniform base.
#define GLDS(g, l) __builtin_amdgcn_global_load_lds( \
    (const __attribute__((address_space(1))) void*)(g), \
    (__attribute__((address_space(3))) void*)(l), 16, 0, 0)

// ---------------------------------------------------------------- fused cvt f32->bf16
__global__ __launch_bounds__(256) void cvt_all(const float* __restrict__ hs,
                                               const float* __restrict__ wq,
                                               const float* __restrict__ wk,
                                               const float* __restrict__ wv,
                                               const float* __restrict__ wg,
                                               const float* __restrict__ wo,
                                               unsigned short* __restrict__ hsb,
                                               unsigned short* __restrict__ wcat,
                                               unsigned short* __restrict__ wob) {
  const long stride = (long)gridDim.x * 256;
  for (long x = (long)blockIdx.x * 256 + threadIdx.x; x < 5767168L; x += stride) {
    const float* src; unsigned short* dst; long off;
    if (x < 2097152L)      { src = hs; dst = hsb;            off = x; }
    else if (x < 3145728L) { src = wq; dst = wcat;           off = x - 2097152L; }
    else if (x < 3407872L) { src = wk; dst = wcat + 4194304; off = x - 3145728L; }
    else if (x < 3670016L) { src = wv; dst = wcat + 5242880; off = x - 3407872L; }
    else if (x < 4718592L) { src = wg; dst = wcat + 6291456; off = x - 3670016L; }
    else                   { src = wo; dst = wob;            off = x - 4718592L; }
    float4 v = ((const float4*)src)[off];
    ushort4 o;
    o.x = f2bf(v.x); o.y = f2bf(v.y); o.z = f2bf(v.z); o.w = f2bf(v.w);
    ((ushort4*)dst)[off] = o;
  }
}

// ---------------------------------------------------------------- NT GEMM (proven 128^2)
// C[M][N] = A[M][K]bf16 * B[N][K]bf16^T.  128x128 tile, BK=64, 4 waves,
// single-buffered with __syncthreads (best for the big QKVG shape).
template <int BF16_OUT>
__global__ __launch_bounds__(256) void gemm_bt(const unsigned short* __restrict__ A,
                                               const unsigned short* __restrict__ Bm,
                                               void* __restrict__ Cv,
                                               int M, int N, int K) {
  __shared__ __align__(16) char lsA[16384];
  __shared__ __align__(16) char lsB[16384];
  const int tid = threadIdx.x;
  const int lane = tid & 63;
  const int wid = tid >> 6;
  const int m0 = blockIdx.y * 128;
  const int n0 = blockIdx.x * 128;
  const size_t ldb = (size_t)K * 2;   // bytes per row
  const char* Abase = (const char*)A + (size_t)m0 * ldb;
  const char* Bbase = (const char*)Bm + (size_t)n0 * ldb;

  f32x4 acc[4][4] = {};

  for (int k0 = 0; k0 < K; k0 += 64) {
#pragma unroll
    for (int i = 0; i < 4; ++i) {
      int xb = i * 4096 + wid * 1024;       // wave-uniform chunk base
      int x  = xb + lane * 16;
      int r  = x >> 7;                      // tile row 0..127
      int c  = (x & 127) ^ ((r & 7) << 4);  // inverse-swizzled source col (bytes)
      GLDS(Abase + (size_t)r * ldb + (size_t)k0 * 2 + c, lsA + xb);
      GLDS(Bbase + (size_t)r * ldb + (size_t)k0 * 2 + c, lsB + xb);
    }
    __syncthreads();
#pragma unroll
    for (int kk = 0; kk < 2; ++kk) {
      bf16x8 afr[4], bfr[4];
#pragma unroll
      for (int i = 0; i < 4; ++i) {
        int ra = (wid >> 1) * 64 + i * 16 + (lane & 15);
        int ca = (kk * 64 + (lane >> 4) * 16) ^ ((ra & 7) << 4);
        afr[i] = *(const bf16x8*)(lsA + ra * 128 + ca);
        int rb = (wid & 1) * 64 + i * 16 + (lane & 15);
        int cb = (kk * 64 + (lane >> 4) * 16) ^ ((rb & 7) << 4);
        bfr[i] = *(const bf16x8*)(lsB + rb * 128 + cb);
      }
#pragma unroll
      for (int i = 0; i < 4; ++i)
#pragma unroll
        for (int j = 0; j < 4; ++j)
          acc[i][j] = __builtin_amdgcn_mfma_f32_16x16x32_bf16(afr[i], bfr[j], acc[i][j], 0, 0, 0);
    }
    __syncthreads();
  }

  const int mb = m0 + (wid >> 1) * 64;
  const int nb = n0 + (wid & 1) * 64;
#pragma unroll
  for (int i = 0; i < 4; ++i)
#pragma unroll
    for (int j = 0; j < 4; ++j)
#pragma unroll
      for (int r = 0; r < 4; ++r) {
        int row = mb + i * 16 + (lane >> 4) * 4 + r;
        int col = nb + j * 16 + (lane & 15);
        if constexpr (BF16_OUT)
          ((unsigned short*)Cv)[(size_t)row * N + col] = f2bf(acc[i][j][r]);
        else
          ((float*)Cv)[(size_t)row * N + col] = acc[i][j][r];
      }
}

// ---------------------------------------------------------------- NT GEMM, 128^2 + T4
// Double-buffered + counted vmcnt (best for the out-proj shape: 512-block
// grid = exactly 2 clean dispatch rounds).
template <int BF16_OUT>
__global__ __launch_bounds__(256) void gemm_db(const unsigned short* __restrict__ A,
                                               const unsigned short* __restrict__ Bm,
                                               void* __restrict__ Cv,
                                               int M, int N, int K) {
  __shared__ __align__(16) char lsA[2][16384];
  __shared__ __align__(16) char lsB[2][16384];
  const int tid = threadIdx.x;
  const int lane = tid & 63;
  const int wid = tid >> 6;
  const int m0 = blockIdx.y * 128;
  const int n0 = blockIdx.x * 128;
  const size_t ldb = (size_t)K * 2;   // bytes per row
  const char* Abase = (const char*)A + (size_t)m0 * ldb;
  const char* Bbase = (const char*)Bm + (size_t)n0 * ldb;
  const int nK = K >> 6;

  f32x4 acc[4][4] = {};

  auto stage = [&](int buf, int kt) {
#pragma unroll
    for (int i = 0; i < 4; ++i) {
      int xb = i * 4096 + wid * 1024;
      int x  = xb + lane * 16;
      int r  = x >> 7;
      int c  = (x & 127) ^ ((r & 7) << 4);
      GLDS(Abase + (size_t)r * ldb + (size_t)kt * 128 + c, lsA[buf] + xb);
      GLDS(Bbase + (size_t)r * ldb + (size_t)kt * 128 + c, lsB[buf] + xb);
    }
  };

  stage(0, 0);
  stage(1, 1);

  for (int t = 0; t < nK; ++t) {
    if (t + 1 < nK)
      asm volatile("s_waitcnt vmcnt(8)\ns_barrier" ::: "memory");
    else
      asm volatile("s_waitcnt vmcnt(0)\ns_barrier" ::: "memory");

    const char* curA = lsA[t & 1];
    const char* curB = lsB[t & 1];
#pragma unroll
    for (int kk = 0; kk < 2; ++kk) {
      bf16x8 afr[4], bfr[4];
#pragma unroll
      for (int i = 0; i < 4; ++i) {
        int ra = (wid >> 1) * 64 + i * 16 + (lane & 15);
        int ca = (kk * 64 + (lane >> 4) * 16) ^ ((ra & 7) << 4);
        afr[i] = *(const bf16x8*)(curA + ra * 128 + ca);
        int rb = (wid & 1) * 64 + i * 16 + (lane & 15);
        int cb = (kk * 64 + (lane >> 4) * 16) ^ ((rb & 7) << 4);
        bfr[i] = *(const bf16x8*)(curB + rb * 128 + cb);
      }
      __builtin_amdgcn_s_setprio(1);
#pragma unroll
      for (int i = 0; i < 4; ++i)
#pragma unroll
        for (int j = 0; j < 4; ++j)
          acc[i][j] = __builtin_amdgcn_mfma_f32_16x16x32_bf16(afr[i], bfr[j], acc[i][j], 0, 0, 0);
      __builtin_amdgcn_s_setprio(0);
    }
    asm volatile("s_barrier" ::: "memory");
    if (t + 2 < nK) stage(t & 1, t + 2);
  }

  const int mb = m0 + (wid >> 1) * 64;
  const int nb = n0 + (wid & 1) * 64;
#pragma unroll
  for (int i = 0; i < 4; ++i)
#pragma unroll
    for (int j = 0; j < 4; ++j)
#pragma unroll
      for (int r = 0; r < 4; ++r) {
        int row = mb + i * 16 + (lane >> 4) * 4 + r;
        int col = nb + j * 16 + (lane & 15);
        if constexpr (BF16_OUT)
          ((unsigned short*)Cv)[(size_t)row * N + col] = f2bf(acc[i][j][r]);
        else
          ((float*)Cv)[(size_t)row * N + col] = acc[i][j][r];
      }
}

// ---------------------------------------------------------------- qkv post
__global__ __launch_bounds__(256) void qkv_post(const unsigned short* __restrict__ qkvg,
                                                const float* __restrict__ cosb,
                                                const float* __restrict__ sinb,
                                                const float* __restrict__ qw,
                                                const float* __restrict__ kw,
                                                unsigned short* __restrict__ qo,
                                                unsigned short* __restrict__ ko) {
  const int t = blockIdx.y;                          // 0..4095
  const int slot = blockIdx.x * 4 + (threadIdx.x >> 6);  // 0..19
  const int lane = threadIdx.x & 63;
  const int s = t & (S_LEN - 1);
  const int b = t >> 11;
  const float QSCALE = 0.08838834764831845f * 1.4426950408889634f;
  const unsigned short* x;
  const float* w;
  float extra;
  unsigned short* outp;
  if (slot < NQH) {
    x = qkvg + (size_t)t * NCOLS + slot * HD;
    w = qw;
    extra = QSCALE;
    outp = qo + (((size_t)(b * NQH + slot)) * S_LEN + s) * HD;
  } else {
    int h = slot - NQH;
    x = qkvg + (size_t)t * NCOLS + HID + h * HD;
    w = kw;
    extra = 1.0f;
    outp = ko + (((size_t)(b * NKVH + h)) * S_LEN + s) * HD;
  }
  float x0 = bf2f(x[lane]), x1 = bf2f(x[lane + 64]);
  float ssq = x0 * x0 + x1 * x1;
#pragma unroll
  for (int m = 1; m < 64; m <<= 1) ssq += __shfl_xor(ssq, m);
  float rinv = rsqrtf(ssq * (1.0f / 128.0f) + 1e-6f) * extra;
  float y0 = x0 * rinv * w[lane];
  float y1 = x1 * rinv * w[lane + 64];
  float c0 = cosb[(size_t)s * HD + lane], c1 = cosb[(size_t)s * HD + lane + 64];
  float s0 = sinb[(size_t)s * HD + lane], s1 = sinb[(size_t)s * HD + lane + 64];
  outp[lane]      = f2bf(y0 * c0 - y1 * s0);
  outp[lane + 64] = f2bf(y1 * c1 + y0 * s1);
}

// ---------------------------------------------------------------- V transpose
__global__ __launch_bounds__(256) void v_transpose(const unsigned short* __restrict__ qkvg,
                                                   unsigned short* __restrict__ vT) {
  __shared__ unsigned short tile[64][65];
  const int st = blockIdx.x;     // s-tile 0..31
  const int dt = blockIdx.y;     // d-tile 0..1
  const int bh = blockIdx.z;     // b*4+hkv, 0..7
  const int b = bh >> 2, h = bh & 3;
  const int tx = threadIdx.x & 63;
  const int ty = threadIdx.x >> 6;    // 0..3
  const int s0 = st * 64, d0 = dt * 64;
#pragma unroll
  for (int ii = 0; ii < 16; ++ii) {
    int sl = ty * 16 + ii;
    tile[sl][tx] = qkvg[(size_t)(b * S_LEN + s0 + sl) * NCOLS + HID + 512 + h * HD + d0 + tx];
  }
  __syncthreads();
#pragma unroll
  for (int ii = 0; ii < 16; ++ii) {
    int dl = ty * 16 + ii;
    vT[((size_t)bh * HD + d0 + dl) * S_LEN + s0 + tx] = tile[tx][dl];
  }
}

// ---------------------------------------------------------------- flash pieces
// SWAPPED QK^T: sc[cb] = mfma(K, Q) -> S^T with col=q=lane&15,
// row=k=(lane>>4)*4+r within block cb. Packed ds_write_b64 P staging.
// Fixed-max softmax: q pre-scaled by scale*log2e; p = exp2(s-66), -66 folded
// into MFMA C-init. Row-sum is a per-lane scalar, reduced in the epilogue.

// single-step (only one Q-tile active this iteration)
__device__ __forceinline__ void attn_step(const bf16x8 (&qf)[4], f32x4 (&o)[8],
                                          float& lsum,
                                          const char* lK, const char* lV, char* lPw,
                                          int lane, int kv0, int qcol, bool diag) {
  const f32x4 minit = {-66.f, -66.f, -66.f, -66.f};
  f32x4 sc[4] = {minit, minit, minit, minit};
  __builtin_amdgcn_s_setprio(1);
#pragma unroll
  for (int cb = 0; cb < 4; ++cb) {
#pragma unroll
    for (int kc = 0; kc < 4; ++kc) {
      int rk = cb * 16 + (lane & 15);
      int ck = (kc * 64 + (lane >> 4) * 16) ^ ((rk & 15) << 4);
      bf16x8 kf = *(const bf16x8*)(lK + rk * 256 + ck);
      sc[cb] = __builtin_amdgcn_mfma_f32_16x16x32_bf16(kf, qf[kc], sc[cb], 0, 0, 0);
    }
  }
  __builtin_amdgcn_s_setprio(0);
  const int kbase_l = kv0 + (lane >> 4) * 4;
  if (diag) {
#pragma unroll
    for (int cb = 0; cb < 4; ++cb)
#pragma unroll
      for (int r = 0; r < 4; ++r)
        if (kbase_l + cb * 16 + r > qcol) sc[cb][r] = -1e30f;
  }
#pragma unroll
  for (int cb = 0; cb < 4; ++cb)
#pragma unroll
    for (int r = 0; r < 4; ++r) {
      float pv = exp2f(sc[cb][r]);
      sc[cb][r] = pv;
      lsum += pv;
    }
  const int q = lane & 15;
  const int g8 = (lane >> 4) * 8;
#pragma unroll
  for (int cb = 0; cb < 4; ++cb) {
    unsigned int lo = (unsigned int)f2bf(sc[cb][0]) | ((unsigned int)f2bf(sc[cb][1]) << 16);
    unsigned int hi = (unsigned int)f2bf(sc[cb][2]) | ((unsigned int)f2bf(sc[cb][3]) << 16);
    int cbyte = (cb * 32 + g8) ^ ((q & 7) << 4);
    uint2 pk; pk.x = lo; pk.y = hi;
    *(uint2*)(lPw + q * 128 + cbyte) = pk;
  }
  asm volatile("s_waitcnt lgkmcnt(0)" ::: "memory");
  __builtin_amdgcn_s_setprio(1);
#pragma unroll
  for (int kc2 = 0; kc2 < 2; ++kc2) {
    int pr = lane & 15;
    int pc = (kc2 * 64 + (lane >> 4) * 16) ^ ((pr & 7) << 4);
    bf16x8 pf = *(const bf16x8*)(lPw + pr * 128 + pc);
#pragma unroll
    for (int db = 0; db < 8; ++db) {
      int vr = db * 16 + (lane & 15);
      int vc = (kc2 * 64 + (lane >> 4) * 16) ^ ((vr & 7) << 4);
      bf16x8 vf = *(const bf16x8*)(lV + vr * 128 + vc);
      o[db] = __builtin_amdgcn_mfma_f32_16x16x32_bf16(pf, vf, o[db], 0, 0, 0);
    }
  }
  __builtin_amdgcn_s_setprio(0);
}

// fused step: both Q-tiles active. K/V fragments loaded ONCE, fed to both.
__device__ __forceinline__ void fused_step(const bf16x8 (&qfA)[4], const bf16x8 (&qfB)[4],
                                           f32x4 (&oA)[8], f32x4 (&oB)[8],
                                           float& lsumA, float& lsumB,
                                           const char* lK, const char* lV,
                                           char* lPa, char* lPb,
                                           int lane, int kv0, int qcolA, int qcolB,
                                           bool diagA, bool diagB) {
  const f32x4 minit = {-66.f, -66.f, -66.f, -66.f};
  f32x4 scA[4] = {minit, minit, minit, minit};
  f32x4 scB[4] = {minit, minit, minit, minit};
  __builtin_amdgcn_s_setprio(1);
#pragma unroll
  for (int cb = 0; cb < 4; ++cb) {
#pragma unroll
    for (int kc = 0; kc < 4; ++kc) {
      int rk = cb * 16 + (lane & 15);
      int ck = (kc * 64 + (lane >> 4) * 16) ^ ((rk & 15) << 4);
      bf16x8 kf = *(const bf16x8*)(lK + rk * 256 + ck);
      scA[cb] = __builtin_amdgcn_mfma_f32_16x16x32_bf16(kf, qfA[kc], scA[cb], 0, 0, 0);
      scB[cb] = __builtin_amdgcn_mfma_f32_16x16x32_bf16(kf, qfB[kc], scB[cb], 0, 0, 0);
    }
  }
  __builtin_amdgcn_s_setprio(0);
  const int kbase_l = kv0 + (lane >> 4) * 4;
  if (diagA) {
#pragma unroll
    for (int cb = 0; cb < 4; ++cb)
#pragma unroll
      for (int r = 0; r < 4; ++r)
        if (kbase_l + cb * 16 + r > qcolA) scA[cb][r] = -1e30f;
  }
  if (diagB) {
#pragma unroll
    for (int cb = 0; cb < 4; ++cb)
#pragma unroll
      for (int r = 0; r < 4; ++r)
        if (kbase_l + cb * 16 + r > qcolB) scB[cb][r] = -1e30f;
  }
#pragma unroll
  for (int cb = 0; cb < 4; ++cb)
#pragma unroll
    for (int r = 0; r < 4; ++r) {
      float pa = exp2f(scA[cb][r]);
      float pb = exp2f(scB[cb][r]);
      scA[cb][r] = pa; lsumA += pa;
      scB[cb][r] = pb; lsumB += pb;
    }
  const int q = lane & 15;
  const int g8 = (lane >> 4) * 8;
#pragma unroll
  for (int cb = 0; cb < 4; ++cb) {
    int cbyte = (cb * 32 + g8) ^ ((q & 7) << 4);
    unsigned int aLo = (unsigned int)f2bf(scA[cb][0]) | ((unsigned int)f2bf(scA[cb][1]) << 16);
    unsigned int aHi = (unsigned int)f2bf(scA[cb][2]) | ((unsigned int)f2bf(scA[cb][3]) << 16);
    uint2 pa; pa.x = aLo; pa.y = aHi;
    *(uint2*)(lPa + q * 128 + cbyte) = pa;
    unsigned int bLo = (unsigned int)f2bf(scB[cb][0]) | ((unsigned int)f2bf(scB[cb][1]) << 16);
    unsigned int bHi = (unsigned int)f2bf(scB[cb][2]) | ((unsigned int)f2bf(scB[cb][3]) << 16);
    uint2 pb; pb.x = bLo; pb.y = bHi;
    *(uint2*)(lPb + q * 128 + cbyte) = pb;
  }
  asm volatile("s_waitcnt lgkmcnt(0)" ::: "memory");
  __builtin_amdgcn_s_setprio(1);
#pragma unroll
  for (int kc2 = 0; kc2 < 2; ++kc2) {
    int pr = lane & 15;
    int pc = (kc2 * 64 + (lane >> 4) * 16) ^ ((pr & 7) << 4);
    bf16x8 pfA = *(const bf16x8*)(lPa + pr * 128 + pc);
    bf16x8 pfB = *(const bf16x8*)(lPb + pr * 128 + pc);
#pragma unroll
    for (int db = 0; db < 8; ++db) {
      int vr = db * 16 + (lane & 15);
      int vc = (kc2 * 64 + (lane >> 4) * 16) ^ ((vr & 7) << 4);
      bf16x8 vf = *(const bf16x8*)(lV + vr * 128 + vc);
      oA[db] = __builtin_amdgcn_mfma_f32_16x16x32_bf16(pfA, vf, oA[db], 0, 0, 0);
      oB[db] = __builtin_amdgcn_mfma_f32_16x16x32_bf16(pfB, vf, oB[db], 0, 0, 0);
    }
  }
  __builtin_amdgcn_s_setprio(0);
}

__device__ __forceinline__ void attn_epilogue(const f32x4 (&o)[8], float lsum,
                                              const unsigned short* __restrict__ qkvg,
                                              unsigned short* __restrict__ ag,
                                              int b, int h, int q0, int wl, int lane) {
  // lsum holds partial sum for q = lane&15; full sum = reduce over lane>>4
  float l = lsum;
  l += __shfl_xor(l, 16);
  l += __shfl_xor(l, 32);
  const int trow_base = b * S_LEN + q0 + wl * 16 + (lane >> 4) * 4;
#pragma unroll
  for (int r = 0; r < 4; ++r) {
    float lr = __shfl(l, (lane >> 4) * 4 + r);
    float inv = 1.0f / lr;
    size_t t = (size_t)(trow_base + r);
#pragma unroll
    for (int db = 0; db < 8; ++db) {
      int col = h * HD + db * 16 + (lane & 15);
      float g = bf2f(qkvg[t * NCOLS + 3072 + col]);
      float sg = 1.0f / (1.0f + expf(-g));
      ag[t * HID + col] = f2bf(o[db][r] * inv * sg);
    }
  }
}

// ---------------------------------------------------------------- flash attention
// 256 blocks x 512 threads (8 waves), 1 block/CU, XCD-local K/V (bid&7 ->
// (b,hkv)).  ADJACENT-TILE PAIRING: wave-group g owns Q-tiles (2J, 2J+1)
// with J = g ? 15-j : j  ->  both tiles are active together for ALL
// iterations except the single diagonal step of the odd tile, so nearly
// every K/V read from LDS feeds two Q-tiles (2x LDS amortization vs the old
// (31-p, p) pairing where the small tile finished immediately).  Per-block
// totals remain exactly 66 tile-units.  K/V double-buffered via GLDS.
__global__ __launch_bounds__(512) void flash(const unsigned short* __restrict__ qg,
                                             const unsigned short* __restrict__ kg,
                                             const unsigned short* __restrict__ vT,
                                             const unsigned short* __restrict__ qkvg,
                                             unsigned short* __restrict__ ag) {
  __shared__ __align__(16) char lK[2][16384];
  __shared__ __align__(16) char lV[2][16384];
  __shared__ __align__(16) char lP[32768];
  const int tid = threadIdx.x, lane = tid & 63, wid = tid >> 6;
  const int g = wid >> 2, wl = wid & 3;
  const int bid = blockIdx.x;           // 0..255
  const int xcd = bid & 7, loc = bid >> 3;
  const int b = xcd >> 2, hkv = xcd & 3;
  const int h = hkv * 4 + (loc & 3);
  const int j = loc >> 2;               // 0..7
  const int J = g ? 15 - j : j;         // pair index for this wave-group
  const int qtA = 2 * J + 1;            // odd (larger) tile
  const int qtB = 2 * J;                // even tile
  const int q0A = qtA * 64, q0B = qtB * 64;
  const int ntA = 2 * j + 2, ntB = 32 - 2 * j;
  const int nt = (ntA > ntB) ? ntA : ntB;   // block-wide iteration count

  const unsigned short* qhead = qg + ((size_t)(b * NQH + h)) * S_LEN * HD;
  bf16x8 qfA[4], qfB[4];
#pragma unroll
  for (int kc = 0; kc < 4; ++kc) {
    qfA[kc] = *(const bf16x8*)(qhead + (size_t)(q0A + wl * 16 + (lane & 15)) * HD +
                               kc * 32 + (lane >> 4) * 8);
    qfB[kc] = *(const bf16x8*)(qhead + (size_t)(q0B + wl * 16 + (lane & 15)) * HD +
                               kc * 32 + (lane >> 4) * 8);
  }

  f32x4 oA[8] = {}, oB[8] = {};
  float lsA = 0.f, lsB = 0.f;

  const char* kbase = (const char*)(kg + ((size_t)(b * NKVH + hkv)) * S_LEN * HD);
  const char* vbase = (const char*)(vT + ((size_t)(b * NKVH + hkv)) * HD * S_LEN);
  char* lPa = lP + wid * 4096;
  char* lPb = lPa + 2048;
  const int qcolA = q0A + wl * 16 + (lane & 15);
  const int qcolB = q0B + wl * 16 + (lane & 15);

  // stage KV tile kv0 into buffer buf (block-wide: 8 waves x 4 GLDS/lane)
  auto stage = [&](int buf, int kv0) {
#pragma unroll
    for (int i = 0; i < 2; ++i) {
      int xb = wid * 2048 + i * 1024;
      int x = xb + lane * 16;
      int rk = x >> 8;
      int ck = (x & 255) ^ ((rk & 15) << 4);
      GLDS(kbase + (size_t)kv0 * 256 + rk * 256 + ck, lK[buf] + xb);
      int rv = x >> 7;
      int cv = (x & 127) ^ ((rv & 7) << 4);
      GLDS(vbase + (size_t)rv * (S_LEN * 2) + kv0 * 2 + cv, lV[buf] + xb);
    }
  };

  stage(0, 0);
  asm volatile("s_waitcnt vmcnt(0)" ::: "memory");
  __syncthreads();

  for (int it = 0; it < nt; ++it) {
    const int cur = it & 1;
    if (it + 1 < nt) stage(cur ^ 1, (it + 1) * 64);   // prefetch next tile

    const bool aA = it <= qtA, aB = it <= qtB;
    if (aA && aB)
      fused_step(qfA, qfB, oA, oB, lsA, lsB, lK[cur], lV[cur], lPa, lPb,
                 lane, it * 64, qcolA, qcolB, it == qtA, it == qtB);
    else if (aA)
      attn_step(qfA, oA, lsA, lK[cur], lV[cur], lPa, lane, it * 64, qcolA, it == qtA);
    else if (aB)
      attn_step(qfB, oB, lsB, lK[cur], lV[cur], lPb, lane, it * 64, qcolB, it == qtB);

    asm volatile("s_waitcnt vmcnt(0)" ::: "memory");
    __syncthreads();
  }

  attn_epilogue(oA, lsA, qkvg, ag, b, h, q0A, wl, lane);
  attn_epilogue(oB, lsB, qkvg, ag, b, h, q0B, wl, lane);
}

// ---------------------------------------------------------------- launch
extern "C" void kernel_launch(void* const* d_in, const int* in_sizes, int n_in,
                              void* d_out, int out_size, void* d_ws, size_t ws_size,
                              hipStream_t stream) {
  const float* hs   = (const float*)d_in[0];
  const float* cosb = (const float*)d_in[1];
  const float* sinb = (const float*)d_in[2];
  const float* Wq   = (const float*)d_in[3];
  const float* Wk   = (const float*)d_in[4];
  const float* Wv   = (const float*)d_in[5];
  const float* Wg   = (const float*)d_in[6];
  const float* Wo   = (const float*)d_in[7];
  const float* qnw  = (const float*)d_in[8];
  const float* knw  = (const float*)d_in[9];

  char* ws = (char*)d_ws;
  unsigned short* hsb  = (unsigned short*)(ws + 0);           // 16.78 MB
  unsigned short* wcat = (unsigned short*)(ws + 16777216);    // 20.97 MB
  unsigned short* wob  = (unsigned short*)(ws + 37748736);    // 8.39 MB
  unsigned short* qb   = (unsigned short*)(ws + 46137344);    // 16.78 MB
  unsigned short* kb   = (unsigned short*)(ws + 62914560);    // 4.19 MB
  unsigned short* vtb  = (unsigned short*)(ws + 67108864);    // 4.19 MB
  unsigned short* agb  = (unsigned short*)(ws + 71303168);    // 16.78 MB
  unsigned short* qkvg = (unsigned short*)(ws + 88080384);    // 41.94 MB (bf16)

  // all f32 -> bf16 conversions in one kernel
  cvt_all<<<2048, 256, 0, stream>>>(hs, Wq, Wk, Wv, Wg, Wo, hsb, wcat, wob);

  // fused QKVG projection: [4096][5120] bf16 = hsb @ wcat^T
  gemm_bt<1><<<dim3(NCOLS / 128, NTOK / 128), 256, 0, stream>>>(hsb, wcat, qkvg,
                                                                NTOK, NCOLS, HID);

  // RMSNorm + RoPE for q,k (q pre-scaled by 1/sqrt(D)*log2e)
  qkv_post<<<dim3(5, NTOK), 256, 0, stream>>>(qkvg, cosb, sinb, qnw, knw, qb, kb);

  // V -> vT
  v_transpose<<<dim3(S_LEN / 64, HD / 64, 2 * NKVH), 256, 0, stream>>>(qkvg, vtb);

  // causal GQA flash attention + sigmoid gate (adjacent-tile pairing)
  flash<<<256, 512, 0, stream>>>(qb, kb, vtb, qkvg, agb);

  // output projection -> d_out (f32)
  gemm_db<0><<<dim3(HID / 128, NTOK / 128), 256, 0, stream>>>(agb, wob, d_out,
                                                              NTOK, HID, HID);
}

// Round 12
// 251.841 us; speedup vs baseline: 1.0070x; 1.0070x over previous
//
#include <hip/hip_runtime.h>

// Problem constants
#define S_LEN 2048
#define NTOK  4096      // B*S = 2*2048
#define HID   2048
#define NQH   16
#define NKVH  4
#define HD    128
#define NCOLS 5120      // 2048 q + 512 k + 512 v + 2048 gate

using bf16x8 = __attribute__((ext_vector_type(8))) __bf16;
using f32x4  = __attribute__((ext_vector_type(4))) float;

__device__ inline unsigned short f2bf(float f) {
  unsigned int u = __builtin_bit_cast(unsigned int, f);
  u += 0x7FFF + ((u >> 16) & 1);   // round-to-nearest-even
  return (unsigned short)(u >> 16);
}
__device__ inline float bf2f(unsigned short u) {
  unsigned int v = (unsigned int)u << 16;
  return __builtin_bit_cast(float, v);
}

// async global->LDS, 16B per lane. LDS ptr must be wave-uniform base.
#define GLDS(g, l) __builtin_amdgcn_global_load_lds( \
    (const __attribute__((address_space(1))) void*)(g), \
    (__attribute__((address_space(3))) void*)(l), 16, 0, 0)

// ---------------------------------------------------------------- fused cvt f32->bf16
__global__ __launch_bounds__(256) void cvt_all(const float* __restrict__ hs,
                                               const float* __restrict__ wq,
                                               const float* __restrict__ wk,
                                               const float* __restrict__ wv,
                                               const float* __restrict__ wg,
                                               const float* __restrict__ wo,
                                               unsigned short* __restrict__ hsb,
                                               unsigned short* __restrict__ wcat,
                                               unsigned short* __restrict__ wob) {
  const long stride = (long)gridDim.x * 256;
  for (long x = (long)blockIdx.x * 256 + threadIdx.x; x < 5767168L; x += stride) {
    const float* src; unsigned short* dst; long off;
    if (x < 2097152L)      { src = hs; dst = hsb;            off = x; }
    else if (x < 3145728L) { src = wq; dst = wcat;           off = x - 2097152L; }
    else if (x < 3407872L) { src = wk; dst = wcat + 4194304; off = x - 3145728L; }
    else if (x < 3670016L) { src = wv; dst = wcat + 5242880; off = x - 3407872L; }
    else if (x < 4718592L) { src = wg; dst = wcat + 6291456; off = x - 3670016L; }
    else                   { src = wo; dst = wob;            off = x - 4718592L; }
    float4 v = ((const float4*)src)[off];
    ushort4 o;
    o.x = f2bf(v.x); o.y = f2bf(v.y); o.z = f2bf(v.z); o.w = f2bf(v.w);
    ((ushort4*)dst)[off] = o;
  }
}

// ---------------------------------------------------------------- NT GEMM (proven 128^2)
// C[M][N] = A[M][K]bf16 * B[N][K]bf16^T.  128x128 tile, BK=64, 4 waves,
// single-buffered with __syncthreads (measured best for the big QKVG shape).
template <int BF16_OUT>
__global__ __launch_bounds__(256) void gemm_bt(const unsigned short* __restrict__ A,
                                               const unsigned short* __restrict__ Bm,
                                               void* __restrict__ Cv,
                                               int M, int N, int K) {
  __shared__ __align__(16) char lsA[16384];
  __shared__ __align__(16) char lsB[16384];
  const int tid = threadIdx.x;
  const int lane = tid & 63;
  const int wid = tid >> 6;
  const int m0 = blockIdx.y * 128;
  const int n0 = blockIdx.x * 128;
  const size_t ldb = (size_t)K * 2;   // bytes per row
  const char* Abase = (const char*)A + (size_t)m0 * ldb;
  const char* Bbase = (const char*)Bm + (size_t)n0 * ldb;

  f32x4 acc[4][4] = {};

  for (int k0 = 0; k0 < K; k0 += 64) {
#pragma unroll
    for (int i = 0; i < 4; ++i) {
      int xb = i * 4096 + wid * 1024;       // wave-uniform chunk base
      int x  = xb + lane * 16;
      int r  = x >> 7;                      // tile row 0..127
      int c  = (x & 127) ^ ((r & 7) << 4);  // inverse-swizzled source col (bytes)
      GLDS(Abase + (size_t)r * ldb + (size_t)k0 * 2 + c, lsA + xb);
      GLDS(Bbase + (size_t)r * ldb + (size_t)k0 * 2 + c, lsB + xb);
    }
    __syncthreads();
#pragma unroll
    for (int kk = 0; kk < 2; ++kk) {
      bf16x8 afr[4], bfr[4];
#pragma unroll
      for (int i = 0; i < 4; ++i) {
        int ra = (wid >> 1) * 64 + i * 16 + (lane & 15);
        int ca = (kk * 64 + (lane >> 4) * 16) ^ ((ra & 7) << 4);
        afr[i] = *(const bf16x8*)(lsA + ra * 128 + ca);
        int rb = (wid & 1) * 64 + i * 16 + (lane & 15);
        int cb = (kk * 64 + (lane >> 4) * 16) ^ ((rb & 7) << 4);
        bfr[i] = *(const bf16x8*)(lsB + rb * 128 + cb);
      }
#pragma unroll
      for (int i = 0; i < 4; ++i)
#pragma unroll
        for (int j = 0; j < 4; ++j)
          acc[i][j] = __builtin_amdgcn_mfma_f32_16x16x32_bf16(afr[i], bfr[j], acc[i][j], 0, 0, 0);
    }
    __syncthreads();
  }

  const int mb = m0 + (wid >> 1) * 64;
  const int nb = n0 + (wid & 1) * 64;
#pragma unroll
  for (int i = 0; i < 4; ++i)
#pragma unroll
    for (int j = 0; j < 4; ++j)
#pragma unroll
      for (int r = 0; r < 4; ++r) {
        int row = mb + i * 16 + (lane >> 4) * 4 + r;
        int col = nb + j * 16 + (lane & 15);
        if constexpr (BF16_OUT)
          ((unsigned short*)Cv)[(size_t)row * N + col] = f2bf(acc[i][j][r]);
        else
          ((float*)Cv)[(size_t)row * N + col] = acc[i][j][r];
      }
}

// ---------------------------------------------------------------- NT GEMM, 128^2 + T4
// Double-buffered + counted vmcnt (measured best for the out-proj shape).
template <int BF16_OUT>
__global__ __launch_bounds__(256) void gemm_db(const unsigned short* __restrict__ A,
                                               const unsigned short* __restrict__ Bm,
                                               void* __restrict__ Cv,
                                               int M, int N, int K) {
  __shared__ __align__(16) char lsA[2][16384];
  __shared__ __align__(16) char lsB[2][16384];
  const int tid = threadIdx.x;
  const int lane = tid & 63;
  const int wid = tid >> 6;
  const int m0 = blockIdx.y * 128;
  const int n0 = blockIdx.x * 128;
  const size_t ldb = (size_t)K * 2;   // bytes per row
  const char* Abase = (const char*)A + (size_t)m0 * ldb;
  const char* Bbase = (const char*)Bm + (size_t)n0 * ldb;
  const int nK = K >> 6;

  f32x4 acc[4][4] = {};

  auto stage = [&](int buf, int kt) {
#pragma unroll
    for (int i = 0; i < 4; ++i) {
      int xb = i * 4096 + wid * 1024;
      int x  = xb + lane * 16;
      int r  = x >> 7;
      int c  = (x & 127) ^ ((r & 7) << 4);
      GLDS(Abase + (size_t)r * ldb + (size_t)kt * 128 + c, lsA[buf] + xb);
      GLDS(Bbase + (size_t)r * ldb + (size_t)kt * 128 + c, lsB[buf] + xb);
    }
  };

  stage(0, 0);
  stage(1, 1);

  for (int t = 0; t < nK; ++t) {
    if (t + 1 < nK)
      asm volatile("s_waitcnt vmcnt(8)\ns_barrier" ::: "memory");
    else
      asm volatile("s_waitcnt vmcnt(0)\ns_barrier" ::: "memory");

    const char* curA = lsA[t & 1];
    const char* curB = lsB[t & 1];
#pragma unroll
    for (int kk = 0; kk < 2; ++kk) {
      bf16x8 afr[4], bfr[4];
#pragma unroll
      for (int i = 0; i < 4; ++i) {
        int ra = (wid >> 1) * 64 + i * 16 + (lane & 15);
        int ca = (kk * 64 + (lane >> 4) * 16) ^ ((ra & 7) << 4);
        afr[i] = *(const bf16x8*)(curA + ra * 128 + ca);
        int rb = (wid & 1) * 64 + i * 16 + (lane & 15);
        int cb = (kk * 64 + (lane >> 4) * 16) ^ ((rb & 7) << 4);
        bfr[i] = *(const bf16x8*)(curB + rb * 128 + cb);
      }
      __builtin_amdgcn_s_setprio(1);
#pragma unroll
      for (int i = 0; i < 4; ++i)
#pragma unroll
        for (int j = 0; j < 4; ++j)
          acc[i][j] = __builtin_amdgcn_mfma_f32_16x16x32_bf16(afr[i], bfr[j], acc[i][j], 0, 0, 0);
      __builtin_amdgcn_s_setprio(0);
    }
    asm volatile("s_barrier" ::: "memory");
    if (t + 2 < nK) stage(t & 1, t + 2);
  }

  const int mb = m0 + (wid >> 1) * 64;
  const int nb = n0 + (wid & 1) * 64;
#pragma unroll
  for (int i = 0; i < 4; ++i)
#pragma unroll
    for (int j = 0; j < 4; ++j)
#pragma unroll
      for (int r = 0; r < 4; ++r) {
        int row = mb + i * 16 + (lane >> 4) * 4 + r;
        int col = nb + j * 16 + (lane & 15);
        if constexpr (BF16_OUT)
          ((unsigned short*)Cv)[(size_t)row * N + col] = f2bf(acc[i][j][r]);
        else
          ((float*)Cv)[(size_t)row * N + col] = acc[i][j][r];
      }
}

// ---------------------------------------------------------------- qkv post
__global__ __launch_bounds__(256) void qkv_post(const unsigned short* __restrict__ qkvg,
                                                const float* __restrict__ cosb,
                                                const float* __restrict__ sinb,
                                                const float* __restrict__ qw,
                                                const float* __restrict__ kw,
                                                unsigned short* __restrict__ qo,
                                                unsigned short* __restrict__ ko) {
  const int t = blockIdx.y;                          // 0..4095
  const int slot = blockIdx.x * 4 + (threadIdx.x >> 6);  // 0..19
  const int lane = threadIdx.x & 63;
  const int s = t & (S_LEN - 1);
  const int b = t >> 11;
  const float QSCALE = 0.08838834764831845f * 1.4426950408889634f;
  const unsigned short* x;
  const float* w;
  float extra;
  unsigned short* outp;
  if (slot < NQH) {
    x = qkvg + (size_t)t * NCOLS + slot * HD;
    w = qw;
    extra = QSCALE;
    outp = qo + (((size_t)(b * NQH + slot)) * S_LEN + s) * HD;
  } else {
    int h = slot - NQH;
    x = qkvg + (size_t)t * NCOLS + HID + h * HD;
    w = kw;
    extra = 1.0f;
    outp = ko + (((size_t)(b * NKVH + h)) * S_LEN + s) * HD;
  }
  float x0 = bf2f(x[lane]), x1 = bf2f(x[lane + 64]);
  float ssq = x0 * x0 + x1 * x1;
#pragma unroll
  for (int m = 1; m < 64; m <<= 1) ssq += __shfl_xor(ssq, m);
  float rinv = rsqrtf(ssq * (1.0f / 128.0f) + 1e-6f) * extra;
  float y0 = x0 * rinv * w[lane];
  float y1 = x1 * rinv * w[lane + 64];
  float c0 = cosb[(size_t)s * HD + lane], c1 = cosb[(size_t)s * HD + lane + 64];
  float s0 = sinb[(size_t)s * HD + lane], s1 = sinb[(size_t)s * HD + lane + 64];
  outp[lane]      = f2bf(y0 * c0 - y1 * s0);
  outp[lane + 64] = f2bf(y1 * c1 + y0 * s1);
}

// ---------------------------------------------------------------- V transpose
__global__ __launch_bounds__(256) void v_transpose(const unsigned short* __restrict__ qkvg,
                                                   unsigned short* __restrict__ vT) {
  __shared__ unsigned short tile[64][65];
  const int st = blockIdx.x;     // s-tile 0..31
  const int dt = blockIdx.y;     // d-tile 0..1
  const int bh = blockIdx.z;     // b*4+hkv, 0..7
  const int b = bh >> 2, h = bh & 3;
  const int tx = threadIdx.x & 63;
  const int ty = threadIdx.x >> 6;    // 0..3
  const int s0 = st * 64, d0 = dt * 64;
#pragma unroll
  for (int ii = 0; ii < 16; ++ii) {
    int sl = ty * 16 + ii;
    tile[sl][tx] = qkvg[(size_t)(b * S_LEN + s0 + sl) * NCOLS + HID + 512 + h * HD + d0 + tx];
  }
  __syncthreads();
#pragma unroll
  for (int ii = 0; ii < 16; ++ii) {
    int dl = ty * 16 + ii;
    vT[((size_t)bh * HD + d0 + dl) * S_LEN + s0 + tx] = tile[tx][dl];
  }
}

// ---------------------------------------------------------------- flash pieces
// SWAPPED QK^T: sc[cb] = mfma(K, Q) -> S^T with col=q=lane&15,
// row=k=(lane>>4)*4+r within block cb. Packed ds_write_b64 P staging.
// Fixed-max softmax: q pre-scaled by scale*log2e; p = exp2(s-66), -66 folded
// into MFMA C-init. Row-sum is a per-lane scalar, reduced in the epilogue.

// single-step (only one Q-tile active this iteration)
__device__ __forceinline__ void attn_step(const bf16x8 (&qf)[4], f32x4 (&o)[8],
                                          float& lsum,
                                          const char* lK, const char* lV, char* lPw,
                                          int lane, int kv0, int qcol, bool diag) {
  const f32x4 minit = {-66.f, -66.f, -66.f, -66.f};
  f32x4 sc[4] = {minit, minit, minit, minit};
  __builtin_amdgcn_s_setprio(1);
#pragma unroll
  for (int cb = 0; cb < 4; ++cb) {
#pragma unroll
    for (int kc = 0; kc < 4; ++kc) {
      int rk = cb * 16 + (lane & 15);
      int ck = (kc * 64 + (lane >> 4) * 16) ^ ((rk & 15) << 4);
      bf16x8 kf = *(const bf16x8*)(lK + rk * 256 + ck);
      sc[cb] = __builtin_amdgcn_mfma_f32_16x16x32_bf16(kf, qf[kc], sc[cb], 0, 0, 0);
    }
  }
  __builtin_amdgcn_s_setprio(0);
  const int kbase_l = kv0 + (lane >> 4) * 4;
  if (diag) {
#pragma unroll
    for (int cb = 0; cb < 4; ++cb)
#pragma unroll
      for (int r = 0; r < 4; ++r)
        if (kbase_l + cb * 16 + r > qcol) sc[cb][r] = -1e30f;
  }
#pragma unroll
  for (int cb = 0; cb < 4; ++cb)
#pragma unroll
    for (int r = 0; r < 4; ++r) {
      float pv = exp2f(sc[cb][r]);
      sc[cb][r] = pv;
      lsum += pv;
    }
  const int q = lane & 15;
  const int g8 = (lane >> 4) * 8;
#pragma unroll
  for (int cb = 0; cb < 4; ++cb) {
    unsigned int lo = (unsigned int)f2bf(sc[cb][0]) | ((unsigned int)f2bf(sc[cb][1]) << 16);
    unsigned int hi = (unsigned int)f2bf(sc[cb][2]) | ((unsigned int)f2bf(sc[cb][3]) << 16);
    int cbyte = (cb * 32 + g8) ^ ((q & 7) << 4);
    uint2 pk; pk.x = lo; pk.y = hi;
    *(uint2*)(lPw + q * 128 + cbyte) = pk;
  }
  asm volatile("s_waitcnt lgkmcnt(0)" ::: "memory");
  __builtin_amdgcn_s_setprio(1);
#pragma unroll
  for (int kc2 = 0; kc2 < 2; ++kc2) {
    int pr = lane & 15;
    int pc = (kc2 * 64 + (lane >> 4) * 16) ^ ((pr & 7) << 4);
    bf16x8 pf = *(const bf16x8*)(lPw + pr * 128 + pc);
#pragma unroll
    for (int db = 0; db < 8; ++db) {
      int vr = db * 16 + (lane & 15);
      int vc = (kc2 * 64 + (lane >> 4) * 16) ^ ((vr & 7) << 4);
      bf16x8 vf = *(const bf16x8*)(lV + vr * 128 + vc);
      o[db] = __builtin_amdgcn_mfma_f32_16x16x32_bf16(pf, vf, o[db], 0, 0, 0);
    }
  }
  __builtin_amdgcn_s_setprio(0);
}

// fused step: both Q-tiles active. K/V fragments loaded ONCE, fed to both.
__device__ __forceinline__ void fused_step(const bf16x8 (&qfA)[4], const bf16x8 (&qfB)[4],
                                           f32x4 (&oA)[8], f32x4 (&oB)[8],
                                           float& lsumA, float& lsumB,
                                           const char* lK, const char* lV,
                                           char* lPa, char* lPb,
                                           int lane, int kv0, int qcolA, int qcolB,
                                           bool diagA, bool diagB) {
  const f32x4 minit = {-66.f, -66.f, -66.f, -66.f};
  f32x4 scA[4] = {minit, minit, minit, minit};
  f32x4 scB[4] = {minit, minit, minit, minit};
  __builtin_amdgcn_s_setprio(1);
#pragma unroll
  for (int cb = 0; cb < 4; ++cb) {
#pragma unroll
    for (int kc = 0; kc < 4; ++kc) {
      int rk = cb * 16 + (lane & 15);
      int ck = (kc * 64 + (lane >> 4) * 16) ^ ((rk & 15) << 4);
      bf16x8 kf = *(const bf16x8*)(lK + rk * 256 + ck);
      scA[cb] = __builtin_amdgcn_mfma_f32_16x16x32_bf16(kf, qfA[kc], scA[cb], 0, 0, 0);
      scB[cb] = __builtin_amdgcn_mfma_f32_16x16x32_bf16(kf, qfB[kc], scB[cb], 0, 0, 0);
    }
  }
  __builtin_amdgcn_s_setprio(0);
  const int kbase_l = kv0 + (lane >> 4) * 4;
  if (diagA) {
#pragma unroll
    for (int cb = 0; cb < 4; ++cb)
#pragma unroll
      for (int r = 0; r < 4; ++r)
        if (kbase_l + cb * 16 + r > qcolA) scA[cb][r] = -1e30f;
  }
  if (diagB) {
#pragma unroll
    for (int cb = 0; cb < 4; ++cb)
#pragma unroll
      for (int r = 0; r < 4; ++r)
        if (kbase_l + cb * 16 + r > qcolB) scB[cb][r] = -1e30f;
  }
#pragma unroll
  for (int cb = 0; cb < 4; ++cb)
#pragma unroll
    for (int r = 0; r < 4; ++r) {
      float pa = exp2f(scA[cb][r]);
      float pb = exp2f(scB[cb][r]);
      scA[cb][r] = pa; lsumA += pa;
      scB[cb][r] = pb; lsumB += pb;
    }
  const int q = lane & 15;
  const int g8 = (lane >> 4) * 8;
#pragma unroll
  for (int cb = 0; cb < 4; ++cb) {
    int cbyte = (cb * 32 + g8) ^ ((q & 7) << 4);
    unsigned int aLo = (unsigned int)f2bf(scA[cb][0]) | ((unsigned int)f2bf(scA[cb][1]) << 16);
    unsigned int aHi = (unsigned int)f2bf(scA[cb][2]) | ((unsigned int)f2bf(scA[cb][3]) << 16);
    uint2 pa; pa.x = aLo; pa.y = aHi;
    *(uint2*)(lPa + q * 128 + cbyte) = pa;
    unsigned int bLo = (unsigned int)f2bf(scB[cb][0]) | ((unsigned int)f2bf(scB[cb][1]) << 16);
    unsigned int bHi = (unsigned int)f2bf(scB[cb][2]) | ((unsigned int)f2bf(scB[cb][3]) << 16);
    uint2 pb; pb.x = bLo; pb.y = bHi;
    *(uint2*)(lPb + q * 128 + cbyte) = pb;
  }
  asm volatile("s_waitcnt lgkmcnt(0)" ::: "memory");
  __builtin_amdgcn_s_setprio(1);
#pragma unroll
  for (int kc2 = 0; kc2 < 2; ++kc2) {
    int pr = lane & 15;
    int pc = (kc2 * 64 + (lane >> 4) * 16) ^ ((pr & 7) << 4);
    bf16x8 pfA = *(const bf16x8*)(lPa + pr * 128 + pc);
    bf16x8 pfB = *(const bf16x8*)(lPb + pr * 128 + pc);
#pragma unroll
    for (int db = 0; db < 8; ++db) {
      int vr = db * 16 + (lane & 15);
      int vc = (kc2 * 64 + (lane >> 4) * 16) ^ ((vr & 7) << 4);
      bf16x8 vf = *(const bf16x8*)(lV + vr * 128 + vc);
      oA[db] = __builtin_amdgcn_mfma_f32_16x16x32_bf16(pfA, vf, oA[db], 0, 0, 0);
      oB[db] = __builtin_amdgcn_mfma_f32_16x16x32_bf16(pfB, vf, oB[db], 0, 0, 0);
    }
  }
  __builtin_amdgcn_s_setprio(0);
}

__device__ __forceinline__ void attn_epilogue(const f32x4 (&o)[8], float lsum,
                                              const unsigned short* __restrict__ qkvg,
                                              unsigned short* __restrict__ ag,
                                              int b, int h, int q0, int wl, int lane) {
  // lsum holds partial sum for q = lane&15; full sum = reduce over lane>>4
  float l = lsum;
  l += __shfl_xor(l, 16);
  l += __shfl_xor(l, 32);
  const int trow_base = b * S_LEN + q0 + wl * 16 + (lane >> 4) * 4;
#pragma unroll
  for (int r = 0; r < 4; ++r) {
    float lr = __shfl(l, (lane >> 4) * 4 + r);
    float inv = 1.0f / lr;
    size_t t = (size_t)(trow_base + r);
#pragma unroll
    for (int db = 0; db < 8; ++db) {
      int col = h * HD + db * 16 + (lane & 15);
      float g = bf2f(qkvg[t * NCOLS + 3072 + col]);
      float sg = 1.0f / (1.0f + expf(-g));
      ag[t * HID + col] = f2bf(o[db][r] * inv * sg);
    }
  }
}

// ---------------------------------------------------------------- flash attention
// 256 blocks x 512 threads (8 waves), 1 block/CU, XCD-local K/V (bid&7 ->
// (b,hkv)). Waves 0-3: Q-tile pair (31-p, p); waves 4-7: (23-p, 8+p) -> every
// wave 33 tile-units (balanced within block; R11's adjacent pairing idled
// half the waves and regressed). K/V double-buffered with COUNTED vmcnt +
// raw barriers: prologue stages tiles 0,1; iter t waits vmcnt(4) (tile t
// landed, t+1's 4 loads stay in flight), computes, barriers, restages t+2.
__global__ __launch_bounds__(512) void flash(const unsigned short* __restrict__ qg,
                                             const unsigned short* __restrict__ kg,
                                             const unsigned short* __restrict__ vT,
                                             const unsigned short* __restrict__ qkvg,
                                             unsigned short* __restrict__ ag) {
  __shared__ __align__(16) char lK[2][16384];
  __shared__ __align__(16) char lV[2][16384];
  __shared__ __align__(16) char lP[32768];
  const int tid = threadIdx.x, lane = tid & 63, wid = tid >> 6;
  const int g = wid >> 2, wl = wid & 3;
  const int bid = blockIdx.x;           // 0..255
  const int xcd = bid & 7, loc = bid >> 3;
  const int b = xcd >> 2, hkv = xcd & 3;
  const int h = hkv * 4 + (loc & 3);
  const int p = loc >> 2;               // 0..7
  const int qtA = g ? 23 - p : 31 - p;
  const int qtB = g ? 8 + p  : p;
  const int q0A = qtA * 64, q0B = qtB * 64;
  const int nt = 32 - p;

  const unsigned short* qhead = qg + ((size_t)(b * NQH + h)) * S_LEN * HD;
  bf16x8 qfA[4], qfB[4];
#pragma unroll
  for (int kc = 0; kc < 4; ++kc) {
    qfA[kc] = *(const bf16x8*)(qhead + (size_t)(q0A + wl * 16 + (lane & 15)) * HD +
                               kc * 32 + (lane >> 4) * 8);
    qfB[kc] = *(const bf16x8*)(qhead + (size_t)(q0B + wl * 16 + (lane & 15)) * HD +
                               kc * 32 + (lane >> 4) * 8);
  }

  f32x4 oA[8] = {}, oB[8] = {};
  float lsA = 0.f, lsB = 0.f;

  const char* kbase = (const char*)(kg + ((size_t)(b * NKVH + hkv)) * S_LEN * HD);
  const char* vbase = (const char*)(vT + ((size_t)(b * NKVH + hkv)) * HD * S_LEN);
  char* lPa = lP + wid * 4096;
  char* lPb = lPa + 2048;
  const int qcolA = q0A + wl * 16 + (lane & 15);
  const int qcolB = q0B + wl * 16 + (lane & 15);

  // stage KV tile kv0 into buffer buf (block-wide: 8 waves x 4 GLDS/lane)
  auto stage = [&](int buf, int kv0) {
#pragma unroll
    for (int i = 0; i < 2; ++i) {
      int xb = wid * 2048 + i * 1024;
      int x = xb + lane * 16;
      int rk = x >> 8;
      int ck = (x & 255) ^ ((rk & 15) << 4);
      GLDS(kbase + (size_t)kv0 * 256 + rk * 256 + ck, lK[buf] + xb);
      int rv = x >> 7;
      int cv = (x & 127) ^ ((rv & 7) << 4);
      GLDS(vbase + (size_t)rv * (S_LEN * 2) + kv0 * 2 + cv, lV[buf] + xb);
    }
  };

  stage(0, 0);
  stage(1, 64);

  for (int it = 0; it < nt; ++it) {
    const int cur = it & 1;
    if (it + 1 < nt)
      asm volatile("s_waitcnt vmcnt(4)\ns_barrier" ::: "memory");
    else
      asm volatile("s_waitcnt vmcnt(0)\ns_barrier" ::: "memory");

    const bool aA = it <= qtA, aB = it <= qtB;
    if (aA && aB)
      fused_step(qfA, qfB, oA, oB, lsA, lsB, lK[cur], lV[cur], lPa, lPb,
                 lane, it * 64, qcolA, qcolB, it == qtA, it == qtB);
    else if (aA)
      attn_step(qfA, oA, lsA, lK[cur], lV[cur], lPa, lane, it * 64, qcolA, it == qtA);
    else if (aB)
      attn_step(qfB, oB, lsB, lK[cur], lV[cur], lPb, lane, it * 64, qcolB, it == qtB);

    asm volatile("s_barrier" ::: "memory");   // all waves done reading buf[cur]
    if (it + 2 < nt) stage(cur, (it + 2) * 64);
  }

  attn_epilogue(oA, lsA, qkvg, ag, b, h, q0A, wl, lane);
  attn_epilogue(oB, lsB, qkvg, ag, b, h, q0B, wl, lane);
}

// ---------------------------------------------------------------- launch
extern "C" void kernel_launch(void* const* d_in, const int* in_sizes, int n_in,
                              void* d_out, int out_size, void* d_ws, size_t ws_size,
                              hipStream_t stream) {
  const float* hs   = (const float*)d_in[0];
  const float* cosb = (const float*)d_in[1];
  const float* sinb = (const float*)d_in[2];
  const float* Wq   = (const float*)d_in[3];
  const float* Wk   = (const float*)d_in[4];
  const float* Wv   = (const float*)d_in[5];
  const float* Wg   = (const float*)d_in[6];
  const float* Wo   = (const float*)d_in[7];
  const float* qnw  = (const float*)d_in[8];
  const float* knw  = (const float*)d_in[9];

  char* ws = (char*)d_ws;
  unsigned short* hsb  = (unsigned short*)(ws + 0);           // 16.78 MB
  unsigned short* wcat = (unsigned short*)(ws + 16777216);    // 20.97 MB
  unsigned short* wob  = (unsigned short*)(ws + 37748736);    // 8.39 MB
  unsigned short* qb   = (unsigned short*)(ws + 46137344);    // 16.78 MB
  unsigned short* kb   = (unsigned short*)(ws + 62914560);    // 4.19 MB
  unsigned short* vtb  = (unsigned short*)(ws + 67108864);    // 4.19 MB
  unsigned short* agb  = (unsigned short*)(ws + 71303168);    // 16.78 MB
  unsigned short* qkvg = (unsigned short*)(ws + 88080384);    // 41.94 MB (bf16)

  // all f32 -> bf16 conversions in one kernel
  cvt_all<<<2048, 256, 0, stream>>>(hs, Wq, Wk, Wv, Wg, Wo, hsb, wcat, wob);

  // fused QKVG projection: [4096][5120] bf16 = hsb @ wcat^T
  gemm_bt<1><<<dim3(NCOLS / 128, NTOK / 128), 256, 0, stream>>>(hsb, wcat, qkvg,
                                                                NTOK, NCOLS, HID);

  // RMSNorm + RoPE for q,k (q pre-scaled by 1/sqrt(D)*log2e)
  qkv_post<<<dim3(5, NTOK), 256, 0, stream>>>(qkvg, cosb, sinb, qnw, knw, qb, kb);

  // V -> vT
  v_transpose<<<dim3(S_LEN / 64, HD / 64, 2 * NKVH), 256, 0, stream>>>(qkvg, vtb);

  // causal GQA flash attention + sigmoid gate (balanced pairing, counted vmcnt)
  flash<<<256, 512, 0, stream>>>(qb, kb, vtb, qkvg, agb);

  // output projection -> d_out (f32)
  gemm_db<0><<<dim3(HID / 128, NTOK / 128), 256, 0, stream>>>(agb, wob, d_out,
                                                              NTOK, HID, HID);
}

// Round 13
// 251.722 us; speedup vs baseline: 1.0075x; 1.0005x over previous
//
#include <hip/hip_runtime.h>

// Problem constants
#define S_LEN 2048
#define NTOK  4096      // B*S = 2*2048
#define HID   2048
#define NQH   16
#define NKVH  4
#define HD    128
#define NCOLS 5120      // 2048 q + 512 k + 512 v + 2048 gate

using bf16x8 = __attribute__((ext_vector_type(8))) __bf16;
using f32x4  = __attribute__((ext_vector_type(4))) float;

__device__ inline unsigned short f2bf(float f) {
  unsigned int u = __builtin_bit_cast(unsigned int, f);
  u += 0x7FFF + ((u >> 16) & 1);   // round-to-nearest-even
  return (unsigned short)(u >> 16);
}
__device__ inline float bf2f(unsigned short u) {
  unsigned int v = (unsigned int)u << 16;
  return __builtin_bit_cast(float, v);
}

// async global->LDS, 16B per lane. LDS ptr must be wave-uniform base.
#define GLDS(g, l) __builtin_amdgcn_global_load_lds( \
    (const __attribute__((address_space(1))) void*)(g), \
    (__attribute__((address_space(3))) void*)(l), 16, 0, 0)

// ---------------------------------------------------------------- fused cvt f32->bf16
__global__ __launch_bounds__(256) void cvt_all(const float* __restrict__ hs,
                                               const float* __restrict__ wq,
                                               const float* __restrict__ wk,
                                               const float* __restrict__ wv,
                                               const float* __restrict__ wg,
                                               const float* __restrict__ wo,
                                               unsigned short* __restrict__ hsb,
                                               unsigned short* __restrict__ wcat,
                                               unsigned short* __restrict__ wob) {
  const long stride = (long)gridDim.x * 256;
  for (long x = (long)blockIdx.x * 256 + threadIdx.x; x < 5767168L; x += stride) {
    const float* src; unsigned short* dst; long off;
    if (x < 2097152L)      { src = hs; dst = hsb;            off = x; }
    else if (x < 3145728L) { src = wq; dst = wcat;           off = x - 2097152L; }
    else if (x < 3407872L) { src = wk; dst = wcat + 4194304; off = x - 3145728L; }
    else if (x < 3670016L) { src = wv; dst = wcat + 5242880; off = x - 3407872L; }
    else if (x < 4718592L) { src = wg; dst = wcat + 6291456; off = x - 3670016L; }
    else                   { src = wo; dst = wob;            off = x - 4718592L; }
    float4 v = ((const float4*)src)[off];
    ushort4 o;
    o.x = f2bf(v.x); o.y = f2bf(v.y); o.z = f2bf(v.z); o.w = f2bf(v.w);
    ((ushort4*)dst)[off] = o;
  }
}

// ---------------------------------------------------------------- NT GEMM (proven 128^2)
// C[M][N] = A[M][K]bf16 * B[N][K]bf16^T.  128x128 tile, BK=64, 4 waves,
// single-buffered with __syncthreads (measured best for the big QKVG shape).
template <int BF16_OUT>
__global__ __launch_bounds__(256) void gemm_bt(const unsigned short* __restrict__ A,
                                               const unsigned short* __restrict__ Bm,
                                               void* __restrict__ Cv,
                                               int M, int N, int K) {
  __shared__ __align__(16) char lsA[16384];
  __shared__ __align__(16) char lsB[16384];
  const int tid = threadIdx.x;
  const int lane = tid & 63;
  const int wid = tid >> 6;
  const int m0 = blockIdx.y * 128;
  const int n0 = blockIdx.x * 128;
  const size_t ldb = (size_t)K * 2;   // bytes per row
  const char* Abase = (const char*)A + (size_t)m0 * ldb;
  const char* Bbase = (const char*)Bm + (size_t)n0 * ldb;

  f32x4 acc[4][4] = {};

  for (int k0 = 0; k0 < K; k0 += 64) {
#pragma unroll
    for (int i = 0; i < 4; ++i) {
      int xb = i * 4096 + wid * 1024;       // wave-uniform chunk base
      int x  = xb + lane * 16;
      int r  = x >> 7;                      // tile row 0..127
      int c  = (x & 127) ^ ((r & 7) << 4);  // inverse-swizzled source col (bytes)
      GLDS(Abase + (size_t)r * ldb + (size_t)k0 * 2 + c, lsA + xb);
      GLDS(Bbase + (size_t)r * ldb + (size_t)k0 * 2 + c, lsB + xb);
    }
    __syncthreads();
#pragma unroll
    for (int kk = 0; kk < 2; ++kk) {
      bf16x8 afr[4], bfr[4];
#pragma unroll
      for (int i = 0; i < 4; ++i) {
        int ra = (wid >> 1) * 64 + i * 16 + (lane & 15);
        int ca = (kk * 64 + (lane >> 4) * 16) ^ ((ra & 7) << 4);
        afr[i] = *(const bf16x8*)(lsA + ra * 128 + ca);
        int rb = (wid & 1) * 64 + i * 16 + (lane & 15);
        int cb = (kk * 64 + (lane >> 4) * 16) ^ ((rb & 7) << 4);
        bfr[i] = *(const bf16x8*)(lsB + rb * 128 + cb);
      }
#pragma unroll
      for (int i = 0; i < 4; ++i)
#pragma unroll
        for (int j = 0; j < 4; ++j)
          acc[i][j] = __builtin_amdgcn_mfma_f32_16x16x32_bf16(afr[i], bfr[j], acc[i][j], 0, 0, 0);
    }
    __syncthreads();
  }

  const int mb = m0 + (wid >> 1) * 64;
  const int nb = n0 + (wid & 1) * 64;
#pragma unroll
  for (int i = 0; i < 4; ++i)
#pragma unroll
    for (int j = 0; j < 4; ++j)
#pragma unroll
      for (int r = 0; r < 4; ++r) {
        int row = mb + i * 16 + (lane >> 4) * 4 + r;
        int col = nb + j * 16 + (lane & 15);
        if constexpr (BF16_OUT)
          ((unsigned short*)Cv)[(size_t)row * N + col] = f2bf(acc[i][j][r]);
        else
          ((float*)Cv)[(size_t)row * N + col] = acc[i][j][r];
      }
}

// ---------------------------------------------------------------- NT GEMM, 128^2 + T4
// Double-buffered + counted vmcnt (measured best for the out-proj shape).
template <int BF16_OUT>
__global__ __launch_bounds__(256) void gemm_db(const unsigned short* __restrict__ A,
                                               const unsigned short* __restrict__ Bm,
                                               void* __restrict__ Cv,
                                               int M, int N, int K) {
  __shared__ __align__(16) char lsA[2][16384];
  __shared__ __align__(16) char lsB[2][16384];
  const int tid = threadIdx.x;
  const int lane = tid & 63;
  const int wid = tid >> 6;
  const int m0 = blockIdx.y * 128;
  const int n0 = blockIdx.x * 128;
  const size_t ldb = (size_t)K * 2;   // bytes per row
  const char* Abase = (const char*)A + (size_t)m0 * ldb;
  const char* Bbase = (const char*)Bm + (size_t)n0 * ldb;
  const int nK = K >> 6;

  f32x4 acc[4][4] = {};

  auto stage = [&](int buf, int kt) {
#pragma unroll
    for (int i = 0; i < 4; ++i) {
      int xb = i * 4096 + wid * 1024;
      int x  = xb + lane * 16;
      int r  = x >> 7;
      int c  = (x & 127) ^ ((r & 7) << 4);
      GLDS(Abase + (size_t)r * ldb + (size_t)kt * 128 + c, lsA[buf] + xb);
      GLDS(Bbase + (size_t)r * ldb + (size_t)kt * 128 + c, lsB[buf] + xb);
    }
  };

  stage(0, 0);
  stage(1, 1);

  for (int t = 0; t < nK; ++t) {
    if (t + 1 < nK)
      asm volatile("s_waitcnt vmcnt(8)\ns_barrier" ::: "memory");
    else
      asm volatile("s_waitcnt vmcnt(0)\ns_barrier" ::: "memory");

    const char* curA = lsA[t & 1];
    const char* curB = lsB[t & 1];
#pragma unroll
    for (int kk = 0; kk < 2; ++kk) {
      bf16x8 afr[4], bfr[4];
#pragma unroll
      for (int i = 0; i < 4; ++i) {
        int ra = (wid >> 1) * 64 + i * 16 + (lane & 15);
        int ca = (kk * 64 + (lane >> 4) * 16) ^ ((ra & 7) << 4);
        afr[i] = *(const bf16x8*)(curA + ra * 128 + ca);
        int rb = (wid & 1) * 64 + i * 16 + (lane & 15);
        int cb = (kk * 64 + (lane >> 4) * 16) ^ ((rb & 7) << 4);
        bfr[i] = *(const bf16x8*)(curB + rb * 128 + cb);
      }
      __builtin_amdgcn_s_setprio(1);
#pragma unroll
      for (int i = 0; i < 4; ++i)
#pragma unroll
        for (int j = 0; j < 4; ++j)
          acc[i][j] = __builtin_amdgcn_mfma_f32_16x16x32_bf16(afr[i], bfr[j], acc[i][j], 0, 0, 0);
      __builtin_amdgcn_s_setprio(0);
    }
    asm volatile("s_barrier" ::: "memory");
    if (t + 2 < nK) stage(t & 1, t + 2);
  }

  const int mb = m0 + (wid >> 1) * 64;
  const int nb = n0 + (wid & 1) * 64;
#pragma unroll
  for (int i = 0; i < 4; ++i)
#pragma unroll
    for (int j = 0; j < 4; ++j)
#pragma unroll
      for (int r = 0; r < 4; ++r) {
        int row = mb + i * 16 + (lane >> 4) * 4 + r;
        int col = nb + j * 16 + (lane & 15);
        if constexpr (BF16_OUT)
          ((unsigned short*)Cv)[(size_t)row * N + col] = f2bf(acc[i][j][r]);
        else
          ((float*)Cv)[(size_t)row * N + col] = acc[i][j][r];
      }
}

// ---------------------------------------------------------------- qkv post
__global__ __launch_bounds__(256) void qkv_post(const unsigned short* __restrict__ qkvg,
                                                const float* __restrict__ cosb,
                                                const float* __restrict__ sinb,
                                                const float* __restrict__ qw,
                                                const float* __restrict__ kw,
                                                unsigned short* __restrict__ qo,
                                                unsigned short* __restrict__ ko) {
  const int t = blockIdx.y;                          // 0..4095
  const int slot = blockIdx.x * 4 + (threadIdx.x >> 6);  // 0..19
  const int lane = threadIdx.x & 63;
  const int s = t & (S_LEN - 1);
  const int b = t >> 11;
  const float QSCALE = 0.08838834764831845f * 1.4426950408889634f;
  const unsigned short* x;
  const float* w;
  float extra;
  unsigned short* outp;
  if (slot < NQH) {
    x = qkvg + (size_t)t * NCOLS + slot * HD;
    w = qw;
    extra = QSCALE;
    outp = qo + (((size_t)(b * NQH + slot)) * S_LEN + s) * HD;
  } else {
    int h = slot - NQH;
    x = qkvg + (size_t)t * NCOLS + HID + h * HD;
    w = kw;
    extra = 1.0f;
    outp = ko + (((size_t)(b * NKVH + h)) * S_LEN + s) * HD;
  }
  float x0 = bf2f(x[lane]), x1 = bf2f(x[lane + 64]);
  float ssq = x0 * x0 + x1 * x1;
#pragma unroll
  for (int m = 1; m < 64; m <<= 1) ssq += __shfl_xor(ssq, m);
  float rinv = rsqrtf(ssq * (1.0f / 128.0f) + 1e-6f) * extra;
  float y0 = x0 * rinv * w[lane];
  float y1 = x1 * rinv * w[lane + 64];
  float c0 = cosb[(size_t)s * HD + lane], c1 = cosb[(size_t)s * HD + lane + 64];
  float s0 = sinb[(size_t)s * HD + lane], s1 = sinb[(size_t)s * HD + lane + 64];
  outp[lane]      = f2bf(y0 * c0 - y1 * s0);
  outp[lane + 64] = f2bf(y1 * c1 + y0 * s1);
}

// ---------------------------------------------------------------- V transpose
__global__ __launch_bounds__(256) void v_transpose(const unsigned short* __restrict__ qkvg,
                                                   unsigned short* __restrict__ vT) {
  __shared__ unsigned short tile[64][65];
  const int st = blockIdx.x;     // s-tile 0..31
  const int dt = blockIdx.y;     // d-tile 0..1
  const int bh = blockIdx.z;     // b*4+hkv, 0..7
  const int b = bh >> 2, h = bh & 3;
  const int tx = threadIdx.x & 63;
  const int ty = threadIdx.x >> 6;    // 0..3
  const int s0 = st * 64, d0 = dt * 64;
#pragma unroll
  for (int ii = 0; ii < 16; ++ii) {
    int sl = ty * 16 + ii;
    tile[sl][tx] = qkvg[(size_t)(b * S_LEN + s0 + sl) * NCOLS + HID + 512 + h * HD + d0 + tx];
  }
  __syncthreads();
#pragma unroll
  for (int ii = 0; ii < 16; ++ii) {
    int dl = ty * 16 + ii;
    vT[((size_t)bh * HD + d0 + dl) * S_LEN + s0 + tx] = tile[tx][dl];
  }
}

// ---------------------------------------------------------------- flash pieces
// SWAPPED QK^T: sc[cb] = mfma(K, Q) -> S^T with col=q=lane&15,
// row=k=(lane>>4)*4+r within block cb. Packed ds_write_b64 P staging.
// Fixed-max softmax: q pre-scaled by scale*log2e; p = exp2(s-66), -66 folded
// into MFMA C-init. Row-sum is a per-lane scalar, reduced in the epilogue.

// single-step (only one Q-tile active this iteration)
__device__ __forceinline__ void attn_step(const bf16x8 (&qf)[4], f32x4 (&o)[8],
                                          float& lsum,
                                          const char* lK, const char* lV, char* lPw,
                                          int lane, int kv0, int qcol, bool diag) {
  const f32x4 minit = {-66.f, -66.f, -66.f, -66.f};
  f32x4 sc[4] = {minit, minit, minit, minit};
  __builtin_amdgcn_s_setprio(1);
#pragma unroll
  for (int cb = 0; cb < 4; ++cb) {
#pragma unroll
    for (int kc = 0; kc < 4; ++kc) {
      int rk = cb * 16 + (lane & 15);
      int ck = (kc * 64 + (lane >> 4) * 16) ^ ((rk & 15) << 4);
      bf16x8 kf = *(const bf16x8*)(lK + rk * 256 + ck);
      sc[cb] = __builtin_amdgcn_mfma_f32_16x16x32_bf16(kf, qf[kc], sc[cb], 0, 0, 0);
    }
  }
  __builtin_amdgcn_s_setprio(0);
  const int kbase_l = kv0 + (lane >> 4) * 4;
  if (diag) {
#pragma unroll
    for (int cb = 0; cb < 4; ++cb)
#pragma unroll
      for (int r = 0; r < 4; ++r)
        if (kbase_l + cb * 16 + r > qcol) sc[cb][r] = -1e30f;
  }
#pragma unroll
  for (int cb = 0; cb < 4; ++cb)
#pragma unroll
    for (int r = 0; r < 4; ++r) {
      float pv = exp2f(sc[cb][r]);
      sc[cb][r] = pv;
      lsum += pv;
    }
  const int q = lane & 15;
  const int g8 = (lane >> 4) * 8;
#pragma unroll
  for (int cb = 0; cb < 4; ++cb) {
    unsigned int lo = (unsigned int)f2bf(sc[cb][0]) | ((unsigned int)f2bf(sc[cb][1]) << 16);
    unsigned int hi = (unsigned int)f2bf(sc[cb][2]) | ((unsigned int)f2bf(sc[cb][3]) << 16);
    int cbyte = (cb * 32 + g8) ^ ((q & 7) << 4);
    uint2 pk; pk.x = lo; pk.y = hi;
    *(uint2*)(lPw + q * 128 + cbyte) = pk;
  }
  asm volatile("s_waitcnt lgkmcnt(0)" ::: "memory");
  __builtin_amdgcn_s_setprio(1);
#pragma unroll
  for (int kc2 = 0; kc2 < 2; ++kc2) {
    int pr = lane & 15;
    int pc = (kc2 * 64 + (lane >> 4) * 16) ^ ((pr & 7) << 4);
    bf16x8 pf = *(const bf16x8*)(lPw + pr * 128 + pc);
#pragma unroll
    for (int db = 0; db < 8; ++db) {
      int vr = db * 16 + (lane & 15);
      int vc = (kc2 * 64 + (lane >> 4) * 16) ^ ((vr & 7) << 4);
      bf16x8 vf = *(const bf16x8*)(lV + vr * 128 + vc);
      o[db] = __builtin_amdgcn_mfma_f32_16x16x32_bf16(pf, vf, o[db], 0, 0, 0);
    }
  }
  __builtin_amdgcn_s_setprio(0);
}

// fused step: both Q-tiles active. K/V fragments loaded ONCE, fed to both.
__device__ __forceinline__ void fused_step(const bf16x8 (&qfA)[4], const bf16x8 (&qfB)[4],
                                           f32x4 (&oA)[8], f32x4 (&oB)[8],
                                           float& lsumA, float& lsumB,
                                           const char* lK, const char* lV,
                                           char* lPa, char* lPb,
                                           int lane, int kv0, int qcolA, int qcolB,
                                           bool diagA, bool diagB) {
  const f32x4 minit = {-66.f, -66.f, -66.f, -66.f};
  f32x4 scA[4] = {minit, minit, minit, minit};
  f32x4 scB[4] = {minit, minit, minit, minit};
  __builtin_amdgcn_s_setprio(1);
#pragma unroll
  for (int cb = 0; cb < 4; ++cb) {
#pragma unroll
    for (int kc = 0; kc < 4; ++kc) {
      int rk = cb * 16 + (lane & 15);
      int ck = (kc * 64 + (lane >> 4) * 16) ^ ((rk & 15) << 4);
      bf16x8 kf = *(const bf16x8*)(lK + rk * 256 + ck);
      scA[cb] = __builtin_amdgcn_mfma_f32_16x16x32_bf16(kf, qfA[kc], scA[cb], 0, 0, 0);
      scB[cb] = __builtin_amdgcn_mfma_f32_16x16x32_bf16(kf, qfB[kc], scB[cb], 0, 0, 0);
    }
  }
  __builtin_amdgcn_s_setprio(0);
  const int kbase_l = kv0 + (lane >> 4) * 4;
  if (diagA) {
#pragma unroll
    for (int cb = 0; cb < 4; ++cb)
#pragma unroll
      for (int r = 0; r < 4; ++r)
        if (kbase_l + cb * 16 + r > qcolA) scA[cb][r] = -1e30f;
  }
  if (diagB) {
#pragma unroll
    for (int cb = 0; cb < 4; ++cb)
#pragma unroll
      for (int r = 0; r < 4; ++r)
        if (kbase_l + cb * 16 + r > qcolB) scB[cb][r] = -1e30f;
  }
#pragma unroll
  for (int cb = 0; cb < 4; ++cb)
#pragma unroll
    for (int r = 0; r < 4; ++r) {
      float pa = exp2f(scA[cb][r]);
      float pb = exp2f(scB[cb][r]);
      scA[cb][r] = pa; lsumA += pa;
      scB[cb][r] = pb; lsumB += pb;
    }
  const int q = lane & 15;
  const int g8 = (lane >> 4) * 8;
#pragma unroll
  for (int cb = 0; cb < 4; ++cb) {
    int cbyte = (cb * 32 + g8) ^ ((q & 7) << 4);
    unsigned int aLo = (unsigned int)f2bf(scA[cb][0]) | ((unsigned int)f2bf(scA[cb][1]) << 16);
    unsigned int aHi = (unsigned int)f2bf(scA[cb][2]) | ((unsigned int)f2bf(scA[cb][3]) << 16);
    uint2 pa; pa.x = aLo; pa.y = aHi;
    *(uint2*)(lPa + q * 128 + cbyte) = pa;
    unsigned int bLo = (unsigned int)f2bf(scB[cb][0]) | ((unsigned int)f2bf(scB[cb][1]) << 16);
    unsigned int bHi = (unsigned int)f2bf(scB[cb][2]) | ((unsigned int)f2bf(scB[cb][3]) << 16);
    uint2 pb; pb.x = bLo; pb.y = bHi;
    *(uint2*)(lPb + q * 128 + cbyte) = pb;
  }
  asm volatile("s_waitcnt lgkmcnt(0)" ::: "memory");
  __builtin_amdgcn_s_setprio(1);
#pragma unroll
  for (int kc2 = 0; kc2 < 2; ++kc2) {
    int pr = lane & 15;
    int pc = (kc2 * 64 + (lane >> 4) * 16) ^ ((pr & 7) << 4);
    bf16x8 pfA = *(const bf16x8*)(lPa + pr * 128 + pc);
    bf16x8 pfB = *(const bf16x8*)(lPb + pr * 128 + pc);
#pragma unroll
    for (int db = 0; db < 8; ++db) {
      int vr = db * 16 + (lane & 15);
      int vc = (kc2 * 64 + (lane >> 4) * 16) ^ ((vr & 7) << 4);
      bf16x8 vf = *(const bf16x8*)(lV + vr * 128 + vc);
      oA[db] = __builtin_amdgcn_mfma_f32_16x16x32_bf16(pfA, vf, oA[db], 0, 0, 0);
      oB[db] = __builtin_amdgcn_mfma_f32_16x16x32_bf16(pfB, vf, oB[db], 0, 0, 0);
    }
  }
  __builtin_amdgcn_s_setprio(0);
}

__device__ __forceinline__ void attn_epilogue(const f32x4 (&o)[8], float lsum,
                                              const unsigned short* __restrict__ qkvg,
                                              unsigned short* __restrict__ ag,
                                              int b, int h, int q0, int wl, int lane) {
  // lsum holds partial sum for q = lane&15; full sum = reduce over lane>>4
  float l = lsum;
  l += __shfl_xor(l, 16);
  l += __shfl_xor(l, 32);
  const int trow_base = b * S_LEN + q0 + wl * 16 + (lane >> 4) * 4;
#pragma unroll
  for (int r = 0; r < 4; ++r) {
    float lr = __shfl(l, (lane >> 4) * 4 + r);
    float inv = 1.0f / lr;
    size_t t = (size_t)(trow_base + r);
#pragma unroll
    for (int db = 0; db < 8; ++db) {
      int col = h * HD + db * 16 + (lane & 15);
      float g = bf2f(qkvg[t * NCOLS + 3072 + col]);
      float sg = 1.0f / (1.0f + expf(-g));
      ag[t * HID + col] = f2bf(o[db][r] * inv * sg);
    }
  }
}

// ---------------------------------------------------------------- flash attention
// 256 blocks x 512 threads (8 waves), 1 block/CU, XCD-local K/V (bid&7 ->
// (b,hkv)). Waves 0-3: Q-tile pair (31-p, p); waves 4-7: (23-p, 8+p) -> every
// wave 33 tile-units (balanced). K/V double-buffered: prefetch issued BEFORE
// compute, drained by the end-of-iter vmcnt(0)+__syncthreads (measured best
// sync form for this kernel; counted-vmcnt variant regressed ~10us in R12).
__global__ __launch_bounds__(512) void flash(const unsigned short* __restrict__ qg,
                                             const unsigned short* __restrict__ kg,
                                             const unsigned short* __restrict__ vT,
                                             const unsigned short* __restrict__ qkvg,
                                             unsigned short* __restrict__ ag) {
  __shared__ __align__(16) char lK[2][16384];
  __shared__ __align__(16) char lV[2][16384];
  __shared__ __align__(16) char lP[32768];
  const int tid = threadIdx.x, lane = tid & 63, wid = tid >> 6;
  const int g = wid >> 2, wl = wid & 3;
  const int bid = blockIdx.x;           // 0..255
  const int xcd = bid & 7, loc = bid >> 3;
  const int b = xcd >> 2, hkv = xcd & 3;
  const int h = hkv * 4 + (loc & 3);
  const int p = loc >> 2;               // 0..7
  const int qtA = g ? 23 - p : 31 - p;
  const int qtB = g ? 8 + p  : p;
  const int q0A = qtA * 64, q0B = qtB * 64;
  const int nt = 32 - p;

  const unsigned short* qhead = qg + ((size_t)(b * NQH + h)) * S_LEN * HD;
  bf16x8 qfA[4], qfB[4];
#pragma unroll
  for (int kc = 0; kc < 4; ++kc) {
    qfA[kc] = *(const bf16x8*)(qhead + (size_t)(q0A + wl * 16 + (lane & 15)) * HD +
                               kc * 32 + (lane >> 4) * 8);
    qfB[kc] = *(const bf16x8*)(qhead + (size_t)(q0B + wl * 16 + (lane & 15)) * HD +
                               kc * 32 + (lane >> 4) * 8);
  }

  f32x4 oA[8] = {}, oB[8] = {};
  float lsA = 0.f, lsB = 0.f;

  const char* kbase = (const char*)(kg + ((size_t)(b * NKVH + hkv)) * S_LEN * HD);
  const char* vbase = (const char*)(vT + ((size_t)(b * NKVH + hkv)) * HD * S_LEN);
  char* lPa = lP + wid * 4096;
  char* lPb = lPa + 2048;
  const int qcolA = q0A + wl * 16 + (lane & 15);
  const int qcolB = q0B + wl * 16 + (lane & 15);

  // stage KV tile kv0 into buffer buf (block-wide: 8 waves x 4 GLDS/lane)
  auto stage = [&](int buf, int kv0) {
#pragma unroll
    for (int i = 0; i < 2; ++i) {
      int xb = wid * 2048 + i * 1024;
      int x = xb + lane * 16;
      int rk = x >> 8;
      int ck = (x & 255) ^ ((rk & 15) << 4);
      GLDS(kbase + (size_t)kv0 * 256 + rk * 256 + ck, lK[buf] + xb);
      int rv = x >> 7;
      int cv = (x & 127) ^ ((rv & 7) << 4);
      GLDS(vbase + (size_t)rv * (S_LEN * 2) + kv0 * 2 + cv, lV[buf] + xb);
    }
  };

  stage(0, 0);
  asm volatile("s_waitcnt vmcnt(0)" ::: "memory");
  __syncthreads();

  for (int it = 0; it < nt; ++it) {
    const int cur = it & 1;
    if (it + 1 < nt) stage(cur ^ 1, (it + 1) * 64);   // prefetch next tile

    const bool aA = it <= qtA, aB = it <= qtB;
    if (aA && aB)
      fused_step(qfA, qfB, oA, oB, lsA, lsB, lK[cur], lV[cur], lPa, lPb,
                 lane, it * 64, qcolA, qcolB, it == qtA, it == qtB);
    else if (aA)
      attn_step(qfA, oA, lsA, lK[cur], lV[cur], lPa, lane, it * 64, qcolA, it == qtA);
    else if (aB)
      attn_step(qfB, oB, lsB, lK[cur], lV[cur], lPb, lane, it * 64, qcolB, it == qtB);

    asm volatile("s_waitcnt vmcnt(0)" ::: "memory");
    __syncthreads();
  }

  attn_epilogue(oA, lsA, qkvg, ag, b, h, q0A, wl, lane);
  attn_epilogue(oB, lsB, qkvg, ag, b, h, q0B, wl, lane);
}

// ---------------------------------------------------------------- launch
extern "C" void kernel_launch(void* const* d_in, const int* in_sizes, int n_in,
                              void* d_out, int out_size, void* d_ws, size_t ws_size,
                              hipStream_t stream) {
  const float* hs   = (const float*)d_in[0];
  const float* cosb = (const float*)d_in[1];
  const float* sinb = (const float*)d_in[2];
  const float* Wq   = (const float*)d_in[3];
  const float* Wk   = (const float*)d_in[4];
  const float* Wv   = (const float*)d_in[5];
  const float* Wg   = (const float*)d_in[6];
  const float* Wo   = (const float*)d_in[7];
  const float* qnw  = (const float*)d_in[8];
  const float* knw  = (const float*)d_in[9];

  char* ws = (char*)d_ws;
  unsigned short* hsb  = (unsigned short*)(ws + 0);           // 16.78 MB
  unsigned short* wcat = (unsigned short*)(ws + 16777216);    // 20.97 MB
  unsigned short* wob  = (unsigned short*)(ws + 37748736);    // 8.39 MB
  unsigned short* qb   = (unsigned short*)(ws + 46137344);    // 16.78 MB
  unsigned short* kb   = (unsigned short*)(ws + 62914560);    // 4.19 MB
  unsigned short* vtb  = (unsigned short*)(ws + 67108864);    // 4.19 MB
  unsigned short* agb  = (unsigned short*)(ws + 71303168);    // 16.78 MB
  unsigned short* qkvg = (unsigned short*)(ws + 88080384);    // 41.94 MB (bf16)

  // all f32 -> bf16 conversions in one kernel
  cvt_all<<<2048, 256, 0, stream>>>(hs, Wq, Wk, Wv, Wg, Wo, hsb, wcat, wob);

  // fused QKVG projection: [4096][5120] bf16 = hsb @ wcat^T
  gemm_bt<1><<<dim3(NCOLS / 128, NTOK / 128), 256, 0, stream>>>(hsb, wcat, qkvg,
                                                                NTOK, NCOLS, HID);

  // RMSNorm + RoPE for q,k (q pre-scaled by 1/sqrt(D)*log2e)
  qkv_post<<<dim3(5, NTOK), 256, 0, stream>>>(qkvg, cosb, sinb, qnw, knw, qb, kb);

  // V -> vT
  v_transpose<<<dim3(S_LEN / 64, HD / 64, 2 * NKVH), 256, 0, stream>>>(qkvg, vtb);

  // causal GQA flash attention + sigmoid gate (R10-measured-best form)
  flash<<<256, 512, 0, stream>>>(qb, kb, vtb, qkvg, agb);

  // output projection -> d_out (f32)
  gemm_db<0><<<dim3(HID / 128, NTOK / 128), 256, 0, stream>>>(agb, wob, d_out,
                                                              NTOK, HID, HID);
}

// Round 14
// 247.466 us; speedup vs baseline: 1.0248x; 1.0172x over previous
//
#include <hip/hip_runtime.h>

// Problem constants
#define S_LEN 2048
#define NTOK  4096      // B*S = 2*2048
#define HID   2048
#define NQH   16
#define NKVH  4
#define HD    128
#define NCOLS 5120      // 2048 q + 512 k + 512 v + 2048 gate

using bf16x8 = __attribute__((ext_vector_type(8))) __bf16;
using f32x4  = __attribute__((ext_vector_type(4))) float;

__device__ inline unsigned short f2bf(float f) {
  unsigned int u = __builtin_bit_cast(unsigned int, f);
  u += 0x7FFF + ((u >> 16) & 1);   // round-to-nearest-even
  return (unsigned short)(u >> 16);
}
__device__ inline float bf2f(unsigned short u) {
  unsigned int v = (unsigned int)u << 16;
  return __builtin_bit_cast(float, v);
}

// async global->LDS, 16B per lane. LDS ptr must be wave-uniform base.
#define GLDS(g, l) __builtin_amdgcn_global_load_lds( \
    (const __attribute__((address_space(1))) void*)(g), \
    (__attribute__((address_space(3))) void*)(l), 16, 0, 0)

// ---------------------------------------------------------------- fused cvt f32->bf16
__global__ __launch_bounds__(256) void cvt_all(const float* __restrict__ hs,
                                               const float* __restrict__ wq,
                                               const float* __restrict__ wk,
                                               const float* __restrict__ wv,
                                               const float* __restrict__ wg,
                                               const float* __restrict__ wo,
                                               unsigned short* __restrict__ hsb,
                                               unsigned short* __restrict__ wcat,
                                               unsigned short* __restrict__ wob) {
  const long stride = (long)gridDim.x * 256;
  for (long x = (long)blockIdx.x * 256 + threadIdx.x; x < 5767168L; x += stride) {
    const float* src; unsigned short* dst; long off;
    if (x < 2097152L)      { src = hs; dst = hsb;            off = x; }
    else if (x < 3145728L) { src = wq; dst = wcat;           off = x - 2097152L; }
    else if (x < 3407872L) { src = wk; dst = wcat + 4194304; off = x - 3145728L; }
    else if (x < 3670016L) { src = wv; dst = wcat + 5242880; off = x - 3407872L; }
    else if (x < 4718592L) { src = wg; dst = wcat + 6291456; off = x - 3670016L; }
    else                   { src = wo; dst = wob;            off = x - 4718592L; }
    float4 v = ((const float4*)src)[off];
    ushort4 o;
    o.x = f2bf(v.x); o.y = f2bf(v.y); o.z = f2bf(v.z); o.w = f2bf(v.w);
    ((ushort4*)dst)[off] = o;
  }
}

// ---------------------------------------------------------------- NT GEMM (proven 128^2)
// C[M][N] = A[M][K]bf16 * B[N][K]bf16^T.  128x128 tile, BK=64, 4 waves,
// single-buffered with __syncthreads (measured best for the big QKVG shape).
template <int BF16_OUT>
__global__ __launch_bounds__(256) void gemm_bt(const unsigned short* __restrict__ A,
                                               const unsigned short* __restrict__ Bm,
                                               void* __restrict__ Cv,
                                               int M, int N, int K) {
  __shared__ __align__(16) char lsA[16384];
  __shared__ __align__(16) char lsB[16384];
  const int tid = threadIdx.x;
  const int lane = tid & 63;
  const int wid = tid >> 6;
  const int m0 = blockIdx.y * 128;
  const int n0 = blockIdx.x * 128;
  const size_t ldb = (size_t)K * 2;   // bytes per row
  const char* Abase = (const char*)A + (size_t)m0 * ldb;
  const char* Bbase = (const char*)Bm + (size_t)n0 * ldb;

  f32x4 acc[4][4] = {};

  for (int k0 = 0; k0 < K; k0 += 64) {
#pragma unroll
    for (int i = 0; i < 4; ++i) {
      int xb = i * 4096 + wid * 1024;       // wave-uniform chunk base
      int x  = xb + lane * 16;
      int r  = x >> 7;                      // tile row 0..127
      int c  = (x & 127) ^ ((r & 7) << 4);  // inverse-swizzled source col (bytes)
      GLDS(Abase + (size_t)r * ldb + (size_t)k0 * 2 + c, lsA + xb);
      GLDS(Bbase + (size_t)r * ldb + (size_t)k0 * 2 + c, lsB + xb);
    }
    __syncthreads();
#pragma unroll
    for (int kk = 0; kk < 2; ++kk) {
      bf16x8 afr[4], bfr[4];
#pragma unroll
      for (int i = 0; i < 4; ++i) {
        int ra = (wid >> 1) * 64 + i * 16 + (lane & 15);
        int ca = (kk * 64 + (lane >> 4) * 16) ^ ((ra & 7) << 4);
        afr[i] = *(const bf16x8*)(lsA + ra * 128 + ca);
        int rb = (wid & 1) * 64 + i * 16 + (lane & 15);
        int cb = (kk * 64 + (lane >> 4) * 16) ^ ((rb & 7) << 4);
        bfr[i] = *(const bf16x8*)(lsB + rb * 128 + cb);
      }
#pragma unroll
      for (int i = 0; i < 4; ++i)
#pragma unroll
        for (int j = 0; j < 4; ++j)
          acc[i][j] = __builtin_amdgcn_mfma_f32_16x16x32_bf16(afr[i], bfr[j], acc[i][j], 0, 0, 0);
    }
    __syncthreads();
  }

  const int mb = m0 + (wid >> 1) * 64;
  const int nb = n0 + (wid & 1) * 64;
#pragma unroll
  for (int i = 0; i < 4; ++i)
#pragma unroll
    for (int j = 0; j < 4; ++j)
#pragma unroll
      for (int r = 0; r < 4; ++r) {
        int row = mb + i * 16 + (lane >> 4) * 4 + r;
        int col = nb + j * 16 + (lane & 15);
        if constexpr (BF16_OUT)
          ((unsigned short*)Cv)[(size_t)row * N + col] = f2bf(acc[i][j][r]);
        else
          ((float*)Cv)[(size_t)row * N + col] = acc[i][j][r];
      }
}

// ---------------------------------------------------------------- NT GEMM, 128^2 + T4
// Double-buffered + counted vmcnt (measured best for the out-proj shape).
template <int BF16_OUT>
__global__ __launch_bounds__(256) void gemm_db(const unsigned short* __restrict__ A,
                                               const unsigned short* __restrict__ Bm,
                                               void* __restrict__ Cv,
                                               int M, int N, int K) {
  __shared__ __align__(16) char lsA[2][16384];
  __shared__ __align__(16) char lsB[2][16384];
  const int tid = threadIdx.x;
  const int lane = tid & 63;
  const int wid = tid >> 6;
  const int m0 = blockIdx.y * 128;
  const int n0 = blockIdx.x * 128;
  const size_t ldb = (size_t)K * 2;   // bytes per row
  const char* Abase = (const char*)A + (size_t)m0 * ldb;
  const char* Bbase = (const char*)Bm + (size_t)n0 * ldb;
  const int nK = K >> 6;

  f32x4 acc[4][4] = {};

  auto stage = [&](int buf, int kt) {
#pragma unroll
    for (int i = 0; i < 4; ++i) {
      int xb = i * 4096 + wid * 1024;
      int x  = xb + lane * 16;
      int r  = x >> 7;
      int c  = (x & 127) ^ ((r & 7) << 4);
      GLDS(Abase + (size_t)r * ldb + (size_t)kt * 128 + c, lsA[buf] + xb);
      GLDS(Bbase + (size_t)r * ldb + (size_t)kt * 128 + c, lsB[buf] + xb);
    }
  };

  stage(0, 0);
  stage(1, 1);

  for (int t = 0; t < nK; ++t) {
    if (t + 1 < nK)
      asm volatile("s_waitcnt vmcnt(8)\ns_barrier" ::: "memory");
    else
      asm volatile("s_waitcnt vmcnt(0)\ns_barrier" ::: "memory");

    const char* curA = lsA[t & 1];
    const char* curB = lsB[t & 1];
#pragma unroll
    for (int kk = 0; kk < 2; ++kk) {
      bf16x8 afr[4], bfr[4];
#pragma unroll
      for (int i = 0; i < 4; ++i) {
        int ra = (wid >> 1) * 64 + i * 16 + (lane & 15);
        int ca = (kk * 64 + (lane >> 4) * 16) ^ ((ra & 7) << 4);
        afr[i] = *(const bf16x8*)(curA + ra * 128 + ca);
        int rb = (wid & 1) * 64 + i * 16 + (lane & 15);
        int cb = (kk * 64 + (lane >> 4) * 16) ^ ((rb & 7) << 4);
        bfr[i] = *(const bf16x8*)(curB + rb * 128 + cb);
      }
      __builtin_amdgcn_s_setprio(1);
#pragma unroll
      for (int i = 0; i < 4; ++i)
#pragma unroll
        for (int j = 0; j < 4; ++j)
          acc[i][j] = __builtin_amdgcn_mfma_f32_16x16x32_bf16(afr[i], bfr[j], acc[i][j], 0, 0, 0);
      __builtin_amdgcn_s_setprio(0);
    }
    asm volatile("s_barrier" ::: "memory");
    if (t + 2 < nK) stage(t & 1, t + 2);
  }

  const int mb = m0 + (wid >> 1) * 64;
  const int nb = n0 + (wid & 1) * 64;
#pragma unroll
  for (int i = 0; i < 4; ++i)
#pragma unroll
    for (int j = 0; j < 4; ++j)
#pragma unroll
      for (int r = 0; r < 4; ++r) {
        int row = mb + i * 16 + (lane >> 4) * 4 + r;
        int col = nb + j * 16 + (lane & 15);
        if constexpr (BF16_OUT)
          ((unsigned short*)Cv)[(size_t)row * N + col] = f2bf(acc[i][j][r]);
        else
          ((float*)Cv)[(size_t)row * N + col] = acc[i][j][r];
      }
}

// ---------------------------------------------------------------- qkv post
// ONE BLOCK PER TOKEN (4 waves x 5 head-slots each). cos/sin/norm-weights are
// loaded into registers ONCE per wave and reused across the 5 slots -- the
// old layout re-read the same 2KB cos/sin 20x per token (~160MB of LLC
// traffic) and launched 20480 blocks. Slot index is wave-uniform per
// iteration, so the q/k branch does not diverge.
__global__ __launch_bounds__(256) void qkv_post(const unsigned short* __restrict__ qkvg,
                                                const float* __restrict__ cosb,
                                                const float* __restrict__ sinb,
                                                const float* __restrict__ qw,
                                                const float* __restrict__ kw,
                                                unsigned short* __restrict__ qo,
                                                unsigned short* __restrict__ ko) {
  const int t = blockIdx.x;                // 0..4095
  const int wid = threadIdx.x >> 6;        // 0..3
  const int lane = threadIdx.x & 63;
  const int s = t & (S_LEN - 1);
  const int b = t >> 11;
  const float QSCALE = 0.08838834764831845f * 1.4426950408889634f;

  const float c0 = cosb[(size_t)s * HD + lane];
  const float c1 = cosb[(size_t)s * HD + lane + 64];
  const float s0 = sinb[(size_t)s * HD + lane];
  const float s1 = sinb[(size_t)s * HD + lane + 64];
  const float wq0 = qw[lane], wq1 = qw[lane + 64];
  const float wk0 = kw[lane], wk1 = kw[lane + 64];

#pragma unroll
  for (int i = 0; i < 5; ++i) {
    const int slot = wid * 5 + i;          // 0..19, wave-uniform
    const unsigned short* x;
    float w0, w1, extra;
    unsigned short* outp;
    if (slot < NQH) {
      x = qkvg + (size_t)t * NCOLS + slot * HD;
      w0 = wq0; w1 = wq1;
      extra = QSCALE;
      outp = qo + (((size_t)(b * NQH + slot)) * S_LEN + s) * HD;
    } else {
      int h = slot - NQH;
      x = qkvg + (size_t)t * NCOLS + HID + h * HD;
      w0 = wk0; w1 = wk1;
      extra = 1.0f;
      outp = ko + (((size_t)(b * NKVH + h)) * S_LEN + s) * HD;
    }
    float x0 = bf2f(x[lane]), x1 = bf2f(x[lane + 64]);
    float ssq = x0 * x0 + x1 * x1;
#pragma unroll
    for (int m = 1; m < 64; m <<= 1) ssq += __shfl_xor(ssq, m);
    float rinv = rsqrtf(ssq * (1.0f / 128.0f) + 1e-6f) * extra;
    float y0 = x0 * rinv * w0;
    float y1 = x1 * rinv * w1;
    outp[lane]      = f2bf(y0 * c0 - y1 * s0);
    outp[lane + 64] = f2bf(y1 * c1 + y0 * s1);
  }
}

// ---------------------------------------------------------------- V transpose
__global__ __launch_bounds__(256) void v_transpose(const unsigned short* __restrict__ qkvg,
                                                   unsigned short* __restrict__ vT) {
  __shared__ unsigned short tile[64][65];
  const int st = blockIdx.x;     // s-tile 0..31
  const int dt = blockIdx.y;     // d-tile 0..1
  const int bh = blockIdx.z;     // b*4+hkv, 0..7
  const int b = bh >> 2, h = bh & 3;
  const int tx = threadIdx.x & 63;
  const int ty = threadIdx.x >> 6;    // 0..3
  const int s0 = st * 64, d0 = dt * 64;
#pragma unroll
  for (int ii = 0; ii < 16; ++ii) {
    int sl = ty * 16 + ii;
    tile[sl][tx] = qkvg[(size_t)(b * S_LEN + s0 + sl) * NCOLS + HID + 512 + h * HD + d0 + tx];
  }
  __syncthreads();
#pragma unroll
  for (int ii = 0; ii < 16; ++ii) {
    int dl = ty * 16 + ii;
    vT[((size_t)bh * HD + d0 + dl) * S_LEN + s0 + tx] = tile[tx][dl];
  }
}

// ---------------------------------------------------------------- flash pieces
// SWAPPED QK^T: sc[cb] = mfma(K, Q) -> S^T with col=q=lane&15,
// row=k=(lane>>4)*4+r within block cb. Packed ds_write_b64 P staging.
// Fixed-max softmax: q pre-scaled by scale*log2e; p = exp2(s-66), -66 folded
// into MFMA C-init. Row-sum is a per-lane scalar, reduced in the epilogue.

// single-step (only one Q-tile active this iteration)
__device__ __forceinline__ void attn_step(const bf16x8 (&qf)[4], f32x4 (&o)[8],
                                          float& lsum,
                                          const char* lK, const char* lV, char* lPw,
                                          int lane, int kv0, int qcol, bool diag) {
  const f32x4 minit = {-66.f, -66.f, -66.f, -66.f};
  f32x4 sc[4] = {minit, minit, minit, minit};
  __builtin_amdgcn_s_setprio(1);
#pragma unroll
  for (int cb = 0; cb < 4; ++cb) {
#pragma unroll
    for (int kc = 0; kc < 4; ++kc) {
      int rk = cb * 16 + (lane & 15);
      int ck = (kc * 64 + (lane >> 4) * 16) ^ ((rk & 15) << 4);
      bf16x8 kf = *(const bf16x8*)(lK + rk * 256 + ck);
      sc[cb] = __builtin_amdgcn_mfma_f32_16x16x32_bf16(kf, qf[kc], sc[cb], 0, 0, 0);
    }
  }
  __builtin_amdgcn_s_setprio(0);
  const int kbase_l = kv0 + (lane >> 4) * 4;
  if (diag) {
#pragma unroll
    for (int cb = 0; cb < 4; ++cb)
#pragma unroll
      for (int r = 0; r < 4; ++r)
        if (kbase_l + cb * 16 + r > qcol) sc[cb][r] = -1e30f;
  }
#pragma unroll
  for (int cb = 0; cb < 4; ++cb)
#pragma unroll
    for (int r = 0; r < 4; ++r) {
      float pv = exp2f(sc[cb][r]);
      sc[cb][r] = pv;
      lsum += pv;
    }
  const int q = lane & 15;
  const int g8 = (lane >> 4) * 8;
#pragma unroll
  for (int cb = 0; cb < 4; ++cb) {
    unsigned int lo = (unsigned int)f2bf(sc[cb][0]) | ((unsigned int)f2bf(sc[cb][1]) << 16);
    unsigned int hi = (unsigned int)f2bf(sc[cb][2]) | ((unsigned int)f2bf(sc[cb][3]) << 16);
    int cbyte = (cb * 32 + g8) ^ ((q & 7) << 4);
    uint2 pk; pk.x = lo; pk.y = hi;
    *(uint2*)(lPw + q * 128 + cbyte) = pk;
  }
  asm volatile("s_waitcnt lgkmcnt(0)" ::: "memory");
  __builtin_amdgcn_s_setprio(1);
#pragma unroll
  for (int kc2 = 0; kc2 < 2; ++kc2) {
    int pr = lane & 15;
    int pc = (kc2 * 64 + (lane >> 4) * 16) ^ ((pr & 7) << 4);
    bf16x8 pf = *(const bf16x8*)(lPw + pr * 128 + pc);
#pragma unroll
    for (int db = 0; db < 8; ++db) {
      int vr = db * 16 + (lane & 15);
      int vc = (kc2 * 64 + (lane >> 4) * 16) ^ ((vr & 7) << 4);
      bf16x8 vf = *(const bf16x8*)(lV + vr * 128 + vc);
      o[db] = __builtin_amdgcn_mfma_f32_16x16x32_bf16(pf, vf, o[db], 0, 0, 0);
    }
  }
  __builtin_amdgcn_s_setprio(0);
}

// fused step: both Q-tiles active. K/V fragments loaded ONCE, fed to both.
__device__ __forceinline__ void fused_step(const bf16x8 (&qfA)[4], const bf16x8 (&qfB)[4],
                                           f32x4 (&oA)[8], f32x4 (&oB)[8],
                                           float& lsumA, float& lsumB,
                                           const char* lK, const char* lV,
                                           char* lPa, char* lPb,
                                           int lane, int kv0, int qcolA, int qcolB,
                                           bool diagA, bool diagB) {
  const f32x4 minit = {-66.f, -66.f, -66.f, -66.f};
  f32x4 scA[4] = {minit, minit, minit, minit};
  f32x4 scB[4] = {minit, minit, minit, minit};
  __builtin_amdgcn_s_setprio(1);
#pragma unroll
  for (int cb = 0; cb < 4; ++cb) {
#pragma unroll
    for (int kc = 0; kc < 4; ++kc) {
      int rk = cb * 16 + (lane & 15);
      int ck = (kc * 64 + (lane >> 4) * 16) ^ ((rk & 15) << 4);
      bf16x8 kf = *(const bf16x8*)(lK + rk * 256 + ck);
      scA[cb] = __builtin_amdgcn_mfma_f32_16x16x32_bf16(kf, qfA[kc], scA[cb], 0, 0, 0);
      scB[cb] = __builtin_amdgcn_mfma_f32_16x16x32_bf16(kf, qfB[kc], scB[cb], 0, 0, 0);
    }
  }
  __builtin_amdgcn_s_setprio(0);
  const int kbase_l = kv0 + (lane >> 4) * 4;
  if (diagA) {
#pragma unroll
    for (int cb = 0; cb < 4; ++cb)
#pragma unroll
      for (int r = 0; r < 4; ++r)
        if (kbase_l + cb * 16 + r > qcolA) scA[cb][r] = -1e30f;
  }
  if (diagB) {
#pragma unroll
    for (int cb = 0; cb < 4; ++cb)
#pragma unroll
      for (int r = 0; r < 4; ++r)
        if (kbase_l + cb * 16 + r > qcolB) scB[cb][r] = -1e30f;
  }
#pragma unroll
  for (int cb = 0; cb < 4; ++cb)
#pragma unroll
    for (int r = 0; r < 4; ++r) {
      float pa = exp2f(scA[cb][r]);
      float pb = exp2f(scB[cb][r]);
      scA[cb][r] = pa; lsumA += pa;
      scB[cb][r] = pb; lsumB += pb;
    }
  const int q = lane & 15;
  const int g8 = (lane >> 4) * 8;
#pragma unroll
  for (int cb = 0; cb < 4; ++cb) {
    int cbyte = (cb * 32 + g8) ^ ((q & 7) << 4);
    unsigned int aLo = (unsigned int)f2bf(scA[cb][0]) | ((unsigned int)f2bf(scA[cb][1]) << 16);
    unsigned int aHi = (unsigned int)f2bf(scA[cb][2]) | ((unsigned int)f2bf(scA[cb][3]) << 16);
    uint2 pa; pa.x = aLo; pa.y = aHi;
    *(uint2*)(lPa + q * 128 + cbyte) = pa;
    unsigned int bLo = (unsigned int)f2bf(scB[cb][0]) | ((unsigned int)f2bf(scB[cb][1]) << 16);
    unsigned int bHi = (unsigned int)f2bf(scB[cb][2]) | ((unsigned int)f2bf(scB[cb][3]) << 16);
    uint2 pb; pb.x = bLo; pb.y = bHi;
    *(uint2*)(lPb + q * 128 + cbyte) = pb;
  }
  asm volatile("s_waitcnt lgkmcnt(0)" ::: "memory");
  __builtin_amdgcn_s_setprio(1);
#pragma unroll
  for (int kc2 = 0; kc2 < 2; ++kc2) {
    int pr = lane & 15;
    int pc = (kc2 * 64 + (lane >> 4) * 16) ^ ((pr & 7) << 4);
    bf16x8 pfA = *(const bf16x8*)(lPa + pr * 128 + pc);
    bf16x8 pfB = *(const bf16x8*)(lPb + pr * 128 + pc);
#pragma unroll
    for (int db = 0; db < 8; ++db) {
      int vr = db * 16 + (lane & 15);
      int vc = (kc2 * 64 + (lane >> 4) * 16) ^ ((vr & 7) << 4);
      bf16x8 vf = *(const bf16x8*)(lV + vr * 128 + vc);
      oA[db] = __builtin_amdgcn_mfma_f32_16x16x32_bf16(pfA, vf, oA[db], 0, 0, 0);
      oB[db] = __builtin_amdgcn_mfma_f32_16x16x32_bf16(pfB, vf, oB[db], 0, 0, 0);
    }
  }
  __builtin_amdgcn_s_setprio(0);
}

__device__ __forceinline__ void attn_epilogue(const f32x4 (&o)[8], float lsum,
                                              const unsigned short* __restrict__ qkvg,
                                              unsigned short* __restrict__ ag,
                                              int b, int h, int q0, int wl, int lane) {
  // lsum holds partial sum for q = lane&15; full sum = reduce over lane>>4
  float l = lsum;
  l += __shfl_xor(l, 16);
  l += __shfl_xor(l, 32);
  const int trow_base = b * S_LEN + q0 + wl * 16 + (lane >> 4) * 4;
#pragma unroll
  for (int r = 0; r < 4; ++r) {
    float lr = __shfl(l, (lane >> 4) * 4 + r);
    float inv = 1.0f / lr;
    size_t t = (size_t)(trow_base + r);
#pragma unroll
    for (int db = 0; db < 8; ++db) {
      int col = h * HD + db * 16 + (lane & 15);
      float g = bf2f(qkvg[t * NCOLS + 3072 + col]);
      float sg = 1.0f / (1.0f + expf(-g));
      ag[t * HID + col] = f2bf(o[db][r] * inv * sg);
    }
  }
}

// ---------------------------------------------------------------- flash attention
// 256 blocks x 512 threads (8 waves), 1 block/CU, XCD-local K/V (bid&7 ->
// (b,hkv)). Waves 0-3: Q-tile pair (31-p, p); waves 4-7: (23-p, 8+p) -> every
// wave 33 tile-units (balanced). K/V double-buffered: prefetch issued BEFORE
// compute, drained by the end-of-iter vmcnt(0)+__syncthreads.
__global__ __launch_bounds__(512) void flash(const unsigned short* __restrict__ qg,
                                             const unsigned short* __restrict__ kg,
                                             const unsigned short* __restrict__ vT,
                                             const unsigned short* __restrict__ qkvg,
                                             unsigned short* __restrict__ ag) {
  __shared__ __align__(16) char lK[2][16384];
  __shared__ __align__(16) char lV[2][16384];
  __shared__ __align__(16) char lP[32768];
  const int tid = threadIdx.x, lane = tid & 63, wid = tid >> 6;
  const int g = wid >> 2, wl = wid & 3;
  const int bid = blockIdx.x;           // 0..255
  const int xcd = bid & 7, loc = bid >> 3;
  const int b = xcd >> 2, hkv = xcd & 3;
  const int h = hkv * 4 + (loc & 3);
  const int p = loc >> 2;               // 0..7
  const int qtA = g ? 23 - p : 31 - p;
  const int qtB = g ? 8 + p  : p;
  const int q0A = qtA * 64, q0B = qtB * 64;
  const int nt = 32 - p;

  const unsigned short* qhead = qg + ((size_t)(b * NQH + h)) * S_LEN * HD;
  bf16x8 qfA[4], qfB[4];
#pragma unroll
  for (int kc = 0; kc < 4; ++kc) {
    qfA[kc] = *(const bf16x8*)(qhead + (size_t)(q0A + wl * 16 + (lane & 15)) * HD +
                               kc * 32 + (lane >> 4) * 8);
    qfB[kc] = *(const bf16x8*)(qhead + (size_t)(q0B + wl * 16 + (lane & 15)) * HD +
                               kc * 32 + (lane >> 4) * 8);
  }

  f32x4 oA[8] = {}, oB[8] = {};
  float lsA = 0.f, lsB = 0.f;

  const char* kbase = (const char*)(kg + ((size_t)(b * NKVH + hkv)) * S_LEN * HD);
  const char* vbase = (const char*)(vT + ((size_t)(b * NKVH + hkv)) * HD * S_LEN);
  char* lPa = lP + wid * 4096;
  char* lPb = lPa + 2048;
  const int qcolA = q0A + wl * 16 + (lane & 15);
  const int qcolB = q0B + wl * 16 + (lane & 15);

  // stage KV tile kv0 into buffer buf (block-wide: 8 waves x 4 GLDS/lane)
  auto stage = [&](int buf, int kv0) {
#pragma unroll
    for (int i = 0; i < 2; ++i) {
      int xb = wid * 2048 + i * 1024;
      int x = xb + lane * 16;
      int rk = x >> 8;
      int ck = (x & 255) ^ ((rk & 15) << 4);
      GLDS(kbase + (size_t)kv0 * 256 + rk * 256 + ck, lK[buf] + xb);
      int rv = x >> 7;
      int cv = (x & 127) ^ ((rv & 7) << 4);
      GLDS(vbase + (size_t)rv * (S_LEN * 2) + kv0 * 2 + cv, lV[buf] + xb);
    }
  };

  stage(0, 0);
  asm volatile("s_waitcnt vmcnt(0)" ::: "memory");
  __syncthreads();

  for (int it = 0; it < nt; ++it) {
    const int cur = it & 1;
    if (it + 1 < nt) stage(cur ^ 1, (it + 1) * 64);   // prefetch next tile

    const bool aA = it <= qtA, aB = it <= qtB;
    if (aA && aB)
      fused_step(qfA, qfB, oA, oB, lsA, lsB, lK[cur], lV[cur], lPa, lPb,
                 lane, it * 64, qcolA, qcolB, it == qtA, it == qtB);
    else if (aA)
      attn_step(qfA, oA, lsA, lK[cur], lV[cur], lPa, lane, it * 64, qcolA, it == qtA);
    else if (aB)
      attn_step(qfB, oB, lsB, lK[cur], lV[cur], lPb, lane, it * 64, qcolB, it == qtB);

    asm volatile("s_waitcnt vmcnt(0)" ::: "memory");
    __syncthreads();
  }

  attn_epilogue(oA, lsA, qkvg, ag, b, h, q0A, wl, lane);
  attn_epilogue(oB, lsB, qkvg, ag, b, h, q0B, wl, lane);
}

// ---------------------------------------------------------------- launch
extern "C" void kernel_launch(void* const* d_in, const int* in_sizes, int n_in,
                              void* d_out, int out_size, void* d_ws, size_t ws_size,
                              hipStream_t stream) {
  const float* hs   = (const float*)d_in[0];
  const float* cosb = (const float*)d_in[1];
  const float* sinb = (const float*)d_in[2];
  const float* Wq   = (const float*)d_in[3];
  const float* Wk   = (const float*)d_in[4];
  const float* Wv   = (const float*)d_in[5];
  const float* Wg   = (const float*)d_in[6];
  const float* Wo   = (const float*)d_in[7];
  const float* qnw  = (const float*)d_in[8];
  const float* knw  = (const float*)d_in[9];

  char* ws = (char*)d_ws;
  unsigned short* hsb  = (unsigned short*)(ws + 0);           // 16.78 MB
  unsigned short* wcat = (unsigned short*)(ws + 16777216);    // 20.97 MB
  unsigned short* wob  = (unsigned short*)(ws + 37748736);    // 8.39 MB
  unsigned short* qb   = (unsigned short*)(ws + 46137344);    // 16.78 MB
  unsigned short* kb   = (unsigned short*)(ws + 62914560);    // 4.19 MB
  unsigned short* vtb  = (unsigned short*)(ws + 67108864);    // 4.19 MB
  unsigned short* agb  = (unsigned short*)(ws + 71303168);    // 16.78 MB
  unsigned short* qkvg = (unsigned short*)(ws + 88080384);    // 41.94 MB (bf16)

  // all f32 -> bf16 conversions in one kernel
  cvt_all<<<2048, 256, 0, stream>>>(hs, Wq, Wk, Wv, Wg, Wo, hsb, wcat, wob);

  // fused QKVG projection: [4096][5120] bf16 = hsb @ wcat^T
  gemm_bt<1><<<dim3(NCOLS / 128, NTOK / 128), 256, 0, stream>>>(hsb, wcat, qkvg,
                                                                NTOK, NCOLS, HID);

  // RMSNorm + RoPE for q,k (one block per token; cos/sin loaded once/wave)
  qkv_post<<<NTOK, 256, 0, stream>>>(qkvg, cosb, sinb, qnw, knw, qb, kb);

  // V -> vT
  v_transpose<<<dim3(S_LEN / 64, HD / 64, 2 * NKVH), 256, 0, stream>>>(qkvg, vtb);

  // causal GQA flash attention + sigmoid gate
  flash<<<256, 512, 0, stream>>>(qb, kb, vtb, qkvg, agb);

  // output projection -> d_out (f32)
  gemm_db<0><<<dim3(HID / 128, NTOK / 128), 256, 0, stream>>>(agb, wob, d_out,
                                                              NTOK, HID, HID);
}